// Round 16
// baseline (542.311 us; speedup 1.0000x reference)
//
#include <hip/hip_runtime.h>
#include <hip/hip_bf16.h>
#include <hip/hip_fp16.h>

#define HW 128
#define NPX 16384
#define CC 256

typedef short  bf16x8  __attribute__((ext_vector_type(8)));
typedef short  short4v __attribute__((ext_vector_type(4)));
typedef float  f32x4   __attribute__((ext_vector_type(4)));
typedef unsigned int u32x4 __attribute__((ext_vector_type(4)));

// ---- scalar bf16 bit helpers (RNE) ----
static __device__ __forceinline__ short f2bs(float v) {
    union { float f; unsigned u; } x; x.f = v;
    unsigned r = x.u + 0x7FFFu + ((x.u >> 16) & 1u);
    return (short)(r >> 16);
}
static __device__ __forceinline__ float bs2f(short s) {
    union { unsigned u; float f; } x; x.u = ((unsigned)(unsigned short)s) << 16;
    return x.f;
}

// XCD-locality swizzle for gridDim.x==256: 32 consecutive logical blocks
// (16 adjacent image rows) land on one XCD -> halo rows hit that XCD's L2.
// Verified round 5: FETCH 30MB -> 13.9MB on the big convs.
static __device__ __forceinline__ int bx_swz() {
    return ((blockIdx.x & 7) << 5) | (blockIdx.x >> 3);
}

// fp8 e5m2 (v9 fallback path)
struct F8 { unsigned char b; };
__device__ __forceinline__ unsigned char enc8(float v) {
    unsigned short u = __half_as_ushort(__float2half(v));
    unsigned short s = u & 0x8000, mag = u & 0x7FFF;
    mag = (unsigned short)(mag + 0x0080);
    return (unsigned char)((unsigned short)(s | mag) >> 8);
}
__device__ __forceinline__ float dec8(F8 v) {
    return __half2float(__ushort_as_half((unsigned short)(v.b) << 8));
}
__device__ __forceinline__ float ldg_(const float* p) { return *p; }
__device__ __forceinline__ float ldg_(const F8* p)    { return dec8(*p); }

// ORConv rotation: c_ROT[r][k] = RING[(INV[k]-r)&7], RING={0,1,2,5,8,7,6,3}.
__constant__ int c_ROT9[8][9] = {
    {0,1,2,3,4,5,6,7,8},
    {3,0,1,6,4,2,7,8,5},
    {6,3,0,7,4,1,8,5,2},
    {7,6,3,8,4,0,5,2,1},
    {8,7,6,5,4,3,2,1,0},
    {5,8,7,2,4,6,1,0,3},
    {2,5,8,1,4,7,0,3,6},
    {1,2,5,0,4,8,3,6,7},
};

// decode helper: fam_bbox fp32 [5,NPX] + px -> refined rotated box (fp32)
__device__ __forceinline__ void v9_decode_px(
    const float* bbox, int px, float s,
    float& gx, float& gy, float& gw, float& gh, float& ga)
{
    int y = px >> 7, x = px & 127;
    float ax = x * s + 3.5f, ay = y * s + 3.5f;
    float dx = bbox[0 * NPX + px];
    float dy = bbox[1 * NPX + px];
    float dw = bbox[2 * NPX + px];
    float dh = bbox[3 * NPX + px];
    float dt = bbox[4 * NPX + px];
    const float maxr = 13.815510558f;
    dw = fminf(fmaxf(dw, -maxr), maxr);
    dh = fminf(fmaxf(dh, -maxr), maxr);
    gx = dx * 32.f + ax;
    gy = dy * 32.f + ay;
    gw = 32.f * expf(dw);
    gh = 32.f * expf(dh);
    const float PI = 3.14159265358979323846f;
    float m = fmodf(dt + PI * 0.25f, PI);
    if (m < 0.f) m += PI;
    ga = m - PI * 0.25f;
}

// ===========================================================================
// ============================  FINAL FAST PATH  ============================
// Terminal build (6 confirmations, 540-546us band; best 540.1us round 12).
// 8-wave 512-thread conv blocks (16 waves/CU), per-tap A-prefetch,
// async-stage split, XCD swizzle, fused single-launch weight prep, paired
// FAM/ODM branches, depth-2 gather-pipe align. Parameter space mapped
// rounds 3-11: conv-pair floor ~81us across every ILP/TLP/occupancy/
// MFMA-shape knob (regalloc vetoes all full-ILP 16-wave variants; 32x32
// MFMA compiles worse). Plateau is compiler/structural, not HW roofline
// (MfmaUtil 18%, HBM 5%); the next lever is an inline-asm counted-vmcnt
// K-loop — a ground-up rewrite, out of this session's scope. Locked.
// ===========================================================================

// feats [256][16384] fp32 -> xt [16384][256] bf16 (LDS 32x32 tile transpose)
__global__ __launch_bounds__(256) void v10_transpose(
    const float* __restrict__ f, short* __restrict__ xt)
{
    __shared__ float tile[32][33];
    int px0 = blockIdx.x * 32, ci0 = blockIdx.y * 32;
    int tx = threadIdx.x & 31, ty = threadIdx.x >> 5;
#pragma unroll
    for (int i = 0; i < 4; ++i) {
        int ci = ty + i * 8;
        tile[ci][tx] = f[(size_t)(ci0 + ci) * NPX + px0 + tx];
    }
    __syncthreads();
#pragma unroll
    for (int i = 0; i < 4; ++i) {
        int pxr = ty + i * 8;
        xt[(size_t)(px0 + pxr) * 256 + ci0 + tx] = f2bs(tile[tx][pxr]);
    }
}

// weight prep -> wb[t][ocp][ci] bf16 (+ padded bias bb[ocp] fp32)
__global__ __launch_bounds__(256) void v10_prep(
    const float* __restrict__ w, const float* __restrict__ bias,
    short* __restrict__ wb, float* __restrict__ bb,
    int Cout, int Cin, int OCP, int mode)
{
    int g = blockIdx.x * 256 + threadIdx.x;
    if (g < OCP) bb[g] = (g < Cout) ? ((mode == 1) ? bias[g >> 3] : bias[g]) : 0.f;
    int tot = 9 * OCP * Cin;
    if (g >= tot) return;
    int t   = g / (OCP * Cin);
    int rem = g - t * OCP * Cin;
    int oc  = rem / Cin;
    int ci  = rem - oc * Cin;
    float v = 0.f;
    if (oc < Cout) {
        if (mode == 0)      v = w[((size_t)oc * Cin + ci) * 9 + t];
        else if (mode == 1) { int o = oc >> 3, r = oc & 7;
                              v = w[((size_t)o * Cin + ci) * 9 + c_ROT9[r][t]]; }
        else if (t == 4)    v = w[(size_t)oc * Cin + ci];
    }
    wb[g] = f2bs(v);
}

// fused prep: job table. {dst_off(shorts), Cout, Cin, OCP, mode}
__constant__ int c_JOB[14][5] = {
    {0,       256, 256, 256, 0},  //  0 frw0
    {589824,  256, 256, 256, 0},  //  1 frw1
    {1179648, 256, 256, 256, 0},  //  2 fcw0
    {1769472, 256, 256, 256, 0},  //  3 fcw1
    {2359296, 256, 256, 256, 0},  //  4 alw
    {2949120, 256, 256, 256, 1},  //  5 orw
    {3538944, 256, 256, 256, 0},  //  6 drw0
    {4128768, 256, 256, 256, 0},  //  7 drw1
    {4718592, 256, 256, 256, 0},  //  8 dcw1
    {5308416, 5,   256, 64,  2},  //  9 frhw
    {5455872, 15,  256, 64,  2},  // 10 fchw
    {5603328, 5,   256, 64,  0},  // 11 drhw (3x3 head)
    {5750784, 15,  256, 64,  0},  // 12 dchw (3x3 head)
    {5898240, 256, 32,  256, 0},  // 13 dcw0
};

__global__ __launch_bounds__(256) void v12_prepall(
    const float* w0, const float* w1, const float* w2, const float* w3,
    const float* w4, const float* w5, const float* w6, const float* w7,
    const float* w8, const float* w9, const float* w10, const float* w11,
    const float* w12, const float* w13,
    const float* b0, const float* b1, const float* b2, const float* b3,
    const float* b4, const float* b5, const float* b6, const float* b7,
    const float* b8, const float* b9, const float* b10, const float* b11,
    const float* b12, const float* b13,
    short* __restrict__ wball, float* __restrict__ bball)
{
    const float* ws_[14] = {w0,w1,w2,w3,w4,w5,w6,w7,w8,w9,w10,w11,w12,w13};
    const float* bs_[14] = {b0,b1,b2,b3,b4,b5,b6,b7,b8,b9,b10,b11,b12,b13};
    const int j = blockIdx.y;
    const int dst  = c_JOB[j][0];
    const int Cout = c_JOB[j][1];
    const int Cin  = c_JOB[j][2];
    const int OCP  = c_JOB[j][3];
    const int mode = c_JOB[j][4];
    const float* w = ws_[j];
    const float* bias = bs_[j];
    int g = blockIdx.x * 256 + threadIdx.x;
    if (g < OCP) bball[j * 256 + g] = (g < Cout) ? ((mode == 1) ? bias[g >> 3] : bias[g]) : 0.f;
    int tot = 9 * OCP * Cin;
    if (g >= tot) return;
    int t   = g / (OCP * Cin);
    int rem = g - t * OCP * Cin;
    int oc  = rem / Cin;
    int ci  = rem - oc * Cin;
    float v = 0.f;
    if (oc < Cout) {
        if (mode == 0)      v = w[((size_t)oc * Cin + ci) * 9 + t];
        else if (mode == 1) { int o = oc >> 3, r = oc & 7;
                              v = w[((size_t)o * Cin + ci) * 9 + c_ROT9[r][t]]; }
        else if (t == 4)    v = w[(size_t)oc * Cin + ci];
    }
    wball[dst + g] = f2bs(v);
}

// ---------------------------------------------------------------------------
// OCG=2 conv body (proven round 3/5; kept for heads + fallback tiers)
template <int RELU, int HEAD, int ONLY1, int CIN, int OCG>
__device__ __forceinline__ void conv_body(
    short* S,   // [2][7920] shorts
    const short* __restrict__ xin, const short* __restrict__ wb,
    const float* __restrict__ bb, void* __restrict__ outv,
    int CoutAct, int OCP, int bx, int oy)
{
    const int y    = bx >> 1;
    const int xh   = (bx & 1) * 64;
    const int ocb  = oy * 64 * OCG;
    const int tid  = threadIdx.x;
    const int wv   = tid >> 6;
    const int lane = tid & 63;
    const int quad = lane >> 4;
    const int l15  = lane & 15;
    const int ocw  = ocb + wv * 16 * OCG;

    int gofs[4], lofs[4];
#pragma unroll
    for (int i = 0; i < 4; ++i) {
        int e = tid + i * 256;
        gofs[i] = -1; lofs[i] = -1;
        if (e < 792) {
            int pos = e >> 2, part = e & 3;
            int r = pos / 66, c = pos - r * 66;
            int yy = y - 1 + r, xx = xh - 1 + c;
            lofs[i] = (r * 66 + c) * 40 + part * 8;
            if (yy >= 0 && yy < HW && xx >= 0 && xx < HW)
                gofs[i] = (yy * HW + xx) * CIN + part * 8;
        }
    }
    const bf16x8 zf = (bf16x8){0, 0, 0, 0, 0, 0, 0, 0};

    f32x4 acc[4][OCG];
#pragma unroll
    for (int p = 0; p < 4; ++p)
#pragma unroll
        for (int g = 0; g < OCG; ++g) acc[p][g] = (f32x4){0.f, 0.f, 0.f, 0.f};

    {
        bf16x8 st[4];
#pragma unroll
        for (int i = 0; i < 4; ++i) {
            st[i] = zf;
            if (gofs[i] >= 0) st[i] = *(const bf16x8*)(xin + gofs[i]);
        }
#pragma unroll
        for (int i = 0; i < 4; ++i)
            if (lofs[i] >= 0) *(bf16x8*)(&S[lofs[i]]) = st[i];
    }
    bf16x8 a[9][OCG];
#pragma unroll
    for (int t = (ONLY1 ? 4 : 0); t < (ONLY1 ? 5 : 9); ++t)
#pragma unroll
        for (int g = 0; g < OCG; ++g)
            a[t][g] = *(const bf16x8*)(wb +
                ((size_t)(t * OCP + ocw + g * 16 + l15) * CIN + quad * 8));
    __syncthreads();

    const int NST = CIN / 32;
    int cur = 0;
    for (int s = 0; s < NST; ++s) {
        const int cib = s * 32;

        bf16x8 st[4];
        if (s + 1 < NST) {
#pragma unroll
            for (int i = 0; i < 4; ++i) {
                st[i] = zf;
                if (gofs[i] >= 0)
                    st[i] = *(const bf16x8*)(xin + gofs[i] + cib + 32);
            }
        }

#pragma unroll
        for (int t = (ONLY1 ? 4 : 0); t < (ONLY1 ? 5 : 9); ++t) {
            const int r = t / 3, dxk = t % 3 - 1;
#pragma unroll
            for (int p = 0; p < 4; ++p) {
                int c = 1 + p * 16 + l15 + dxk;
                bf16x8 b = *(const bf16x8*)(&S[cur * 7920 + (r * 66 + c) * 40 + quad * 8]);
#pragma unroll
                for (int g = 0; g < OCG; ++g)
                    acc[p][g] = __builtin_amdgcn_mfma_f32_16x16x32_bf16(a[t][g], b, acc[p][g], 0, 0, 0);
            }
            if (s + 1 < NST) {
#pragma unroll
                for (int g = 0; g < OCG; ++g)
                    a[t][g] = *(const bf16x8*)(wb +
                        ((size_t)(t * OCP + ocw + g * 16 + l15) * CIN + cib + 32 + quad * 8));
            }
        }

        if (s + 1 < NST) {
#pragma unroll
            for (int i = 0; i < 4; ++i)
                if (lofs[i] >= 0) *(bf16x8*)(&S[(cur ^ 1) * 7920 + lofs[i]]) = st[i];
        }
        __syncthreads();
        cur ^= 1;
    }

#pragma unroll
    for (int p = 0; p < 4; ++p) {
        const int px = y * HW + xh + p * 16 + l15;
#pragma unroll
        for (int g = 0; g < OCG; ++g) {
            const int ocq = ocw + g * 16 + quad * 4;
            if (HEAD) {
                float* o = (float*)outv;
#pragma unroll
                for (int r = 0; r < 4; ++r)
                    if (ocq + r < CoutAct)
                        o[(size_t)(ocq + r) * NPX + px] = acc[p][g][r] + bb[ocq + r];
            } else {
                short4v s4;
#pragma unroll
                for (int r = 0; r < 4; ++r) {
                    float v = acc[p][g][r] + bb[ocq + r];
                    if (RELU) v = fmaxf(v, 0.f);
                    s4[r] = f2bs(v);
                }
                *(short4v*)((short*)outv + (size_t)px * 256 + ocq) = s4;
            }
        }
    }
}

// ---------------------------------------------------------------------------
// 8-wave conv body (512 threads): 64 px x 256 oc per block, each wave owns
// 32 oc. Per tap: 4 b-frag reads feed 8 MFMAs; aC[2]/aN[2] per-tap
// A-prefetch. 2 blocks/CU -> 16 waves/CU (4/SIMD).
template <int RELU, int CIN>
__device__ __forceinline__ void conv_body8(
    short* S,   // [2][7920] shorts
    const short* __restrict__ xin, const short* __restrict__ wb,
    const float* __restrict__ bb, short* __restrict__ outb, int bx)
{
    const int y    = bx >> 1;
    const int xh   = (bx & 1) * 64;
    const int tid  = threadIdx.x;       // 0..511
    const int wv   = tid >> 6;          // 0..7
    const int lane = tid & 63;
    const int quad = lane >> 4;
    const int l15  = lane & 15;
    const int ocw  = wv * 32;

    // staging: 792 chunks over 512 threads (2 rounds)
    int gofs[2], lofs[2];
#pragma unroll
    for (int i = 0; i < 2; ++i) {
        int e = tid + i * 512;
        gofs[i] = -1; lofs[i] = -1;
        if (e < 792) {
            int pos = e >> 2, part = e & 3;
            int r = pos / 66, c = pos - r * 66;
            int yy = y - 1 + r, xx = xh - 1 + c;
            lofs[i] = (r * 66 + c) * 40 + part * 8;
            if (yy >= 0 && yy < HW && xx >= 0 && xx < HW)
                gofs[i] = (yy * HW + xx) * CIN + part * 8;
        }
    }
    const bf16x8 zf = (bf16x8){0, 0, 0, 0, 0, 0, 0, 0};

    f32x4 acc[4][2];
#pragma unroll
    for (int p = 0; p < 4; ++p) {
        acc[p][0] = (f32x4){0.f, 0.f, 0.f, 0.f};
        acc[p][1] = (f32x4){0.f, 0.f, 0.f, 0.f};
    }

    // prologue: stage slice 0; load A for (t=0, cib=0)
    {
        bf16x8 st[2];
#pragma unroll
        for (int i = 0; i < 2; ++i) {
            st[i] = zf;
            if (gofs[i] >= 0) st[i] = *(const bf16x8*)(xin + gofs[i]);
        }
#pragma unroll
        for (int i = 0; i < 2; ++i)
            if (lofs[i] >= 0) *(bf16x8*)(&S[lofs[i]]) = st[i];
    }
    bf16x8 aC[2], aN[2];
#pragma unroll
    for (int g = 0; g < 2; ++g)
        aC[g] = *(const bf16x8*)(wb +
            ((size_t)(ocw + g * 16 + l15) * CIN + quad * 8));
    aN[0] = aC[0]; aN[1] = aC[1];
    __syncthreads();

    const int NST = CIN / 32;
    int cur = 0;
    for (int s = 0; s < NST; ++s) {
        const int cib = s * 32;

        // issue next-slice staging loads (hide under MFMA phase)
        bf16x8 st[2];
        if (s + 1 < NST) {
#pragma unroll
            for (int i = 0; i < 2; ++i) {
                st[i] = zf;
                if (gofs[i] >= 0)
                    st[i] = *(const bf16x8*)(xin + gofs[i] + cib + 32);
            }
        }

#pragma unroll
        for (int t = 0; t < 9; ++t) {
            // prefetch A for next (tap, slice)
            const int nt   = (t == 8) ? 0 : t + 1;
            const int ncib = (t == 8) ? cib + 32 : cib;
            if (!(s == NST - 1 && t == 8)) {
#pragma unroll
                for (int g = 0; g < 2; ++g)
                    aN[g] = *(const bf16x8*)(wb +
                        ((size_t)(nt * 256 + ocw + g * 16 + l15) * CIN + ncib + quad * 8));
            }
            const int r = t / 3, dxk = t % 3 - 1;
#pragma unroll
            for (int p = 0; p < 4; ++p) {
                int c = 1 + p * 16 + l15 + dxk;
                bf16x8 b = *(const bf16x8*)(&S[cur * 7920 + (r * 66 + c) * 40 + quad * 8]);
                acc[p][0] = __builtin_amdgcn_mfma_f32_16x16x32_bf16(aC[0], b, acc[p][0], 0, 0, 0);
                acc[p][1] = __builtin_amdgcn_mfma_f32_16x16x32_bf16(aC[1], b, acc[p][1], 0, 0, 0);
            }
            aC[0] = aN[0]; aC[1] = aN[1];
        }

        if (s + 1 < NST) {
#pragma unroll
            for (int i = 0; i < 2; ++i)
                if (lofs[i] >= 0) *(bf16x8*)(&S[(cur ^ 1) * 7920 + lofs[i]]) = st[i];
        }
        __syncthreads();
        cur ^= 1;
    }

#pragma unroll
    for (int p = 0; p < 4; ++p) {
        const int px = y * HW + xh + p * 16 + l15;
#pragma unroll
        for (int g = 0; g < 2; ++g) {
            const int ocq = ocw + g * 16 + quad * 4;
            short4v s4;
#pragma unroll
            for (int r = 0; r < 4; ++r) {
                float v = acc[p][g][r] + bb[ocq + r];
                if (RELU) v = fmaxf(v, 0.f);
                s4[r] = f2bs(v);
            }
            *(short4v*)(outb + (size_t)px * 256 + ocq) = s4;
        }
    }
}

// single-branch conv kernel (OCG=2, fallback tiers)
template <int RELU, int HEAD, int ONLY1, int CIN, int OCG>
__global__ __launch_bounds__(256) void v13_conv(
    const short* __restrict__ xin, const short* __restrict__ wb,
    const float* __restrict__ bb, void* __restrict__ outv,
    int CoutAct, int OCP)
{
    __shared__ short S[2 * 7920];
    conv_body<RELU, HEAD, ONLY1, CIN, OCG>(S, xin, wb, bb, outv,
                                           CoutAct, OCP, bx_swz(), blockIdx.y);
}

// paired conv kernel (heads)
template <int RELU, int HEAD, int ONLY1, int CIN0, int CIN1, int OCG, int NY, int OCP>
__global__ __launch_bounds__(256) void v13_pair(
    const short* __restrict__ in0, const short* __restrict__ in1,
    const short* __restrict__ wb0, const short* __restrict__ wb1,
    const float* __restrict__ bb0, const float* __restrict__ bb1,
    void* __restrict__ out0, void* __restrict__ out1,
    int cout0, int cout1)
{
    __shared__ short S[2 * 7920];
    const int ybr = blockIdx.y;
    if (ybr < NY)
        conv_body<RELU, HEAD, ONLY1, CIN0, OCG>(S, in0, wb0, bb0, out0,
                                                cout0, OCP, bx_swz(), ybr);
    else
        conv_body<RELU, HEAD, ONLY1, CIN1, OCG>(S, in1, wb1, bb1, out1,
                                                cout1, OCP, bx_swz(), ybr - NY);
}

// 8-wave kernels (round-8/12 best config: waves_per_eu(4) min-bound).
template <int RELU, int CIN>
__global__ __launch_bounds__(512) __attribute__((amdgpu_waves_per_eu(4)))
void v15_conv(
    const short* __restrict__ xin, const short* __restrict__ wb,
    const float* __restrict__ bb, short* __restrict__ outb)
{
    __shared__ short S[2 * 7920];
    conv_body8<RELU, CIN>(S, xin, wb, bb, outb, bx_swz());
}

template <int RELU, int CIN0, int CIN1>
__global__ __launch_bounds__(512) __attribute__((amdgpu_waves_per_eu(4)))
void v15_pair(
    const short* __restrict__ in0, const short* __restrict__ in1,
    const short* __restrict__ wb0, const short* __restrict__ wb1,
    const float* __restrict__ bb0, const float* __restrict__ bb1,
    short* __restrict__ out0, short* __restrict__ out1)
{
    __shared__ short S[2 * 7920];
    if (blockIdx.y == 0)
        conv_body8<RELU, CIN0>(S, in0, wb0, bb0, out0, bx_swz());
    else
        conv_body8<RELU, CIN1>(S, in1, wb1, bb1, out1, bx_swz());
}

// -------- v13 align: deformable 3x3 conv via MFMA, depth-2 gather pipe ----
__global__ __launch_bounds__(256) void v13_align(
    const short* __restrict__ xt, const float* __restrict__ bbox,
    const short* __restrict__ wb, const float* __restrict__ bb,
    const int* __restrict__ stride_p, short* __restrict__ outa)
{
    const int bx   = bx_swz();
    const int y    = bx >> 1;
    const int xh   = (bx & 1) * 64;
    const int ocb  = blockIdx.y * 128;
    const int tid  = threadIdx.x;
    const int wv   = tid >> 6, lane = tid & 63, quad = lane >> 4, l15 = lane & 15;
    const int ocw  = ocb + wv * 32;

    __shared__ int   s_idx[4][576];
    __shared__ float s_wgt[4][576];
    __shared__ short S[2][64 * 40];

    const float s = (float)(*stride_p);
    for (int e = tid; e < 576; e += 256) {
        int t = e >> 6, xi = e & 63;
        int px = y * HW + xh + xi;
        float gx, gy, gw, gh, ga;
        v9_decode_px(bbox, px, s, gx, gy, gw, gh, ga);
        float axc = gx / s, ayc = gy / s;
        float aw3 = gw / (3.f * s), ah3 = gh / (3.f * s);
        float cs = cosf(ga), sn = sinf(ga);
        float kx = (float)(t % 3 - 1), ky = (float)(t / 3 - 1);
        float ddx = aw3 * kx, ddy = ah3 * ky;
        float xf = cs * ddx - sn * ddy + axc;
        float yf = sn * ddx + cs * ddy + ayc;
        float fx = floorf(xf), fy = floorf(yf);
        int ix = (int)fx, iy = (int)fy;
        float wx1 = xf - fx, wx0 = 1.f - wx1;
        float wy1 = yf - fy, wy0 = 1.f - wy1;
        bool x0v = (ix >= 0) && (ix < HW), x1v = (ix + 1 >= 0) && (ix + 1 < HW);
        bool y0v = (iy >= 0) && (iy < HW), y1v = (iy + 1 >= 0) && (iy + 1 < HW);
        int x0c = min(max(ix, 0), HW - 1), x1c = min(max(ix + 1, 0), HW - 1);
        int y0c = min(max(iy, 0), HW - 1), y1c = min(max(iy + 1, 0), HW - 1);
        s_idx[0][e] = y0c * HW + x0c;
        s_idx[1][e] = y0c * HW + x1c;
        s_idx[2][e] = y1c * HW + x0c;
        s_idx[3][e] = y1c * HW + x1c;
        s_wgt[0][e] = (y0v && x0v) ? wy0 * wx0 : 0.f;
        s_wgt[1][e] = (y0v && x1v) ? wy0 * wx1 : 0.f;
        s_wgt[2][e] = (y1v && x0v) ? wy1 * wx0 : 0.f;
        s_wgt[3][e] = (y1v && x1v) ? wy1 * wx1 : 0.f;
    }

    f32x4 acc[4][2];
#pragma unroll
    for (int p = 0; p < 4; ++p) { acc[p][0] = (f32x4){0,0,0,0}; acc[p][1] = (f32x4){0,0,0,0}; }

    const int spx = tid >> 2;
    const int sq  = tid & 3;
    const int sw  = spx * 40 + sq * 8;
    const bf16x8 zf = (bf16x8){0, 0, 0, 0, 0, 0, 0, 0};

    __syncthreads();

    bf16x8 aC0, aC1;
    bf16x8 gN0, gN1, gN2, gN3;
    float  wN0, wN1, wN2, wN3;
    {
        int e = spx;
        int i0 = s_idx[0][e], i1 = s_idx[1][e], i2 = s_idx[2][e], i3 = s_idx[3][e];
        float w0 = s_wgt[0][e], w1 = s_wgt[1][e], w2 = s_wgt[2][e], w3 = s_wgt[3][e];
        const short* base = xt + sq * 8;
        bf16x8 g0 = *(const bf16x8*)(base + (size_t)i0 * 256);
        bf16x8 g1 = *(const bf16x8*)(base + (size_t)i1 * 256);
        bf16x8 g2 = *(const bf16x8*)(base + (size_t)i2 * 256);
        bf16x8 g3 = *(const bf16x8*)(base + (size_t)i3 * 256);
        float v[8];
#pragma unroll
        for (int i = 0; i < 8; ++i)
            v[i] = w0 * bs2f(g0[i]) + w1 * bs2f(g1[i]) + w2 * bs2f(g2[i]) + w3 * bs2f(g3[i]);
        u32x4 r;
#pragma unroll
        for (int i = 0; i < 4; ++i)
            asm("v_cvt_pk_bf16_f32 %0, %1, %2" : "=v"(r[i]) : "v"(v[2 * i]), "v"(v[2 * i + 1]));
        *(u32x4*)(&S[0][sw]) = r;
    }
    {
        int e = 64 + spx;
        int i0 = s_idx[0][e], i1 = s_idx[1][e], i2 = s_idx[2][e], i3 = s_idx[3][e];
        wN0 = s_wgt[0][e]; wN1 = s_wgt[1][e]; wN2 = s_wgt[2][e]; wN3 = s_wgt[3][e];
        const short* base = xt + sq * 8;
        gN0 = *(const bf16x8*)(base + (size_t)i0 * 256);
        gN1 = *(const bf16x8*)(base + (size_t)i1 * 256);
        gN2 = *(const bf16x8*)(base + (size_t)i2 * 256);
        gN3 = *(const bf16x8*)(base + (size_t)i3 * 256);
    }
    aC0 = *(const bf16x8*)(wb + ((size_t)(ocw + l15) * 256 + quad * 8));
    aC1 = *(const bf16x8*)(wb + ((size_t)(ocw + 16 + l15) * 256 + quad * 8));
    __syncthreads();

    int cur = 0;
    for (int cib = 0; cib < 256; cib += 32) {
        for (int t = 0; t < 9; ++t) {
            const bool have1 = !(cib == 224 && t == 8);
            const bool have2 = !(cib == 224 && t >= 7);
            const int t1 = (t == 8) ? 0 : t + 1;
            const int c1 = (t == 8) ? cib + 32 : cib;
            int t2 = t + 2, c2 = cib;
            if (t2 > 8) { t2 -= 9; c2 += 32; }

            bf16x8 gF0 = zf, gF1 = zf, gF2 = zf, gF3 = zf;
            float  wF0 = 0.f, wF1 = 0.f, wF2 = 0.f, wF3 = 0.f;
            if (have2) {
                int e = t2 * 64 + spx;
                int i0 = s_idx[0][e], i1 = s_idx[1][e], i2 = s_idx[2][e], i3 = s_idx[3][e];
                wF0 = s_wgt[0][e]; wF1 = s_wgt[1][e]; wF2 = s_wgt[2][e]; wF3 = s_wgt[3][e];
                const short* base = xt + c2 + sq * 8;
                gF0 = *(const bf16x8*)(base + (size_t)i0 * 256);
                gF1 = *(const bf16x8*)(base + (size_t)i1 * 256);
                gF2 = *(const bf16x8*)(base + (size_t)i2 * 256);
                gF3 = *(const bf16x8*)(base + (size_t)i3 * 256);
            }
            bf16x8 aN0 = aC0, aN1 = aC1;
            if (have1) {
                aN0 = *(const bf16x8*)(wb + ((size_t)(t1 * 256 + ocw + l15) * 256 + c1 + quad * 8));
                aN1 = *(const bf16x8*)(wb + ((size_t)(t1 * 256 + ocw + 16 + l15) * 256 + c1 + quad * 8));
            }

#pragma unroll
            for (int p = 0; p < 4; ++p) {
                bf16x8 b = *(const bf16x8*)(&S[cur][(p * 16 + l15) * 40 + quad * 8]);
                acc[p][0] = __builtin_amdgcn_mfma_f32_16x16x32_bf16(aC0, b, acc[p][0], 0, 0, 0);
                acc[p][1] = __builtin_amdgcn_mfma_f32_16x16x32_bf16(aC1, b, acc[p][1], 0, 0, 0);
            }

            if (have1) {
                float v[8];
#pragma unroll
                for (int i = 0; i < 8; ++i)
                    v[i] = wN0 * bs2f(gN0[i]) + wN1 * bs2f(gN1[i])
                         + wN2 * bs2f(gN2[i]) + wN3 * bs2f(gN3[i]);
                u32x4 r;
#pragma unroll
                for (int i = 0; i < 4; ++i)
                    asm("v_cvt_pk_bf16_f32 %0, %1, %2" : "=v"(r[i]) : "v"(v[2 * i]), "v"(v[2 * i + 1]));
                *(u32x4*)(&S[cur ^ 1][sw]) = r;
            }
            gN0 = gF0; gN1 = gF1; gN2 = gF2; gN3 = gF3;
            wN0 = wF0; wN1 = wF1; wN2 = wF2; wN3 = wF3;
            aC0 = aN0; aC1 = aN1;
            cur ^= 1;
            __syncthreads();
        }
    }

#pragma unroll
    for (int p = 0; p < 4; ++p) {
        const int px = y * HW + xh + p * 16 + l15;
#pragma unroll
        for (int g = 0; g < 2; ++g) {
            const int ocq = ocw + g * 16 + quad * 4;
            short4v s4;
#pragma unroll
            for (int r = 0; r < 4; ++r)
                s4[r] = f2bs(fmaxf(acc[p][g][r] + bb[ocq + r], 0.f));
            *(short4v*)(outa + (size_t)px * 256 + ocq) = s4;
        }
    }
}

// pool: T [px][256] bf16 -> P [px][32] bf16 (max over 8 consecutive oc)
__global__ __launch_bounds__(256) void v10_pool(
    const short* __restrict__ t1, short* __restrict__ p)
{
    int g = blockIdx.x * 256 + threadIdx.x;
    if (g >= 32 * NPX) return;
    int px = g >> 5, c = g & 31;
    const short* q = t1 + (size_t)px * 256 + c * 8;
    float m = bs2f(q[0]);
#pragma unroll
    for (int r = 1; r < 8; ++r) m = fmaxf(m, bs2f(q[r]));
    p[(size_t)px * 32 + c] = f2bs(m);
}

// anchors + refine decode -> fp32 d_out (shared by both paths)
__global__ __launch_bounds__(256) void v9_decode(
    const float* __restrict__ bbox, float* __restrict__ anchors_out,
    float* __restrict__ refine_out, const int* __restrict__ stride_p)
{
    int px = blockIdx.x * 256 + threadIdx.x;
    if (px >= NPX) return;
    float s = (float)(*stride_p);
    int y = px >> 7, x = px & 127;
    anchors_out[px * 5 + 0] = x * s + 3.5f;
    anchors_out[px * 5 + 1] = y * s + 3.5f;
    anchors_out[px * 5 + 2] = 32.f;
    anchors_out[px * 5 + 3] = 32.f;
    anchors_out[px * 5 + 4] = 0.f;
    float gx, gy, gw, gh, ga;
    v9_decode_px(bbox, px, s, gx, gy, gw, gh, ga);
    refine_out[px * 5 + 0] = gx;
    refine_out[px * 5 + 1] = gy;
    refine_out[px * 5 + 2] = gw;
    refine_out[px * 5 + 3] = gh;
    refine_out[px * 5 + 4] = ga;
}

// ===========================================================================
// ============  V9 FALLBACK (verbatim from passing round 9)  ================
// ===========================================================================
template <typename TIN, int RELU, int ORCONV>
__global__ __launch_bounds__(256) void v9_conv3x3(
    const TIN* __restrict__ in, const float* __restrict__ w,
    const float* __restrict__ bias, F8* __restrict__ out, int Cin)
{
    const int y   = blockIdx.x;
    const int ocb = blockIdx.y * 64;
    const int tid = threadIdx.x;
    const int xg  = tid & 15;
    const int og  = tid >> 4;
    const int x0  = xg * 8;
    const int oc0 = ocb + og * 4;

    __shared__ float srow[3][132];
    float acc[4][8];
#pragma unroll
    for (int i = 0; i < 4; ++i)
#pragma unroll
        for (int j = 0; j < 8; ++j) acc[i][j] = 0.f;

    for (int ci = 0; ci < Cin; ++ci) {
        __syncthreads();
        const TIN* inp = in + (size_t)ci * NPX;
        for (int t = tid; t < 3 * 130; t += 256) {
            int r = t / 130, c = t - r * 130;
            int yy = y - 1 + r, xx = c - 1;
            float v = 0.f;
            if (yy >= 0 && yy < HW && xx >= 0 && xx < HW) v = ldg_(inp + yy * HW + xx);
            srow[r][c] = v;
        }
        __syncthreads();
        float wv[4][9];
#pragma unroll
        for (int i = 0; i < 4; ++i) {
            if (ORCONV) {
                int oc = oc0 + i;
                const float* wp = w + ((size_t)(oc >> 3) * Cin + ci) * 9;
                const int* rot = c_ROT9[oc & 7];
#pragma unroll
                for (int k = 0; k < 9; ++k) wv[i][k] = wp[rot[k]];
            } else {
                const float* wp = w + ((size_t)(oc0 + i) * Cin + ci) * 9;
#pragma unroll
                for (int k = 0; k < 9; ++k) wv[i][k] = wp[k];
            }
        }
#pragma unroll
        for (int r = 0; r < 3; ++r) {
            float iv[10];
#pragma unroll
            for (int c = 0; c < 10; ++c) iv[c] = srow[r][x0 + c];
#pragma unroll
            for (int dxk = 0; dxk < 3; ++dxk)
#pragma unroll
                for (int i = 0; i < 4; ++i)
#pragma unroll
                    for (int j = 0; j < 8; ++j)
                        acc[i][j] += iv[j + dxk] * wv[i][r * 3 + dxk];
        }
    }
#pragma unroll
    for (int i = 0; i < 4; ++i) {
        float b = ORCONV ? bias[(oc0 + i) >> 3] : bias[oc0 + i];
#pragma unroll
        for (int j = 0; j < 8; ++j) {
            float v = acc[i][j] + b;
            if (RELU) v = fmaxf(v, 0.f);
            out[(size_t)(oc0 + i) * NPX + y * HW + x0 + j].b = enc8(v);
        }
    }
}

__global__ __launch_bounds__(256) void v9_head1x1(
    const F8* __restrict__ in, const float* __restrict__ w,
    const float* __restrict__ bias, float* __restrict__ out, int Cout)
{
    int g = blockIdx.x * 256 + threadIdx.x;
    if (g >= Cout * NPX) return;
    int px = g & (NPX - 1);
    int oc = g >> 14;
    float acc = bias[oc];
    const float* wp = w + (size_t)oc * CC;
    for (int ci = 0; ci < CC; ++ci)
        acc += dec8(in[(size_t)ci * NPX + px]) * wp[ci];
    out[g] = acc;
}

__global__ __launch_bounds__(256) void v9_head3x3(
    const F8* __restrict__ in, const float* __restrict__ w,
    const float* __restrict__ bias, float* __restrict__ out, int Cout)
{
    int g = blockIdx.x * 256 + threadIdx.x;
    if (g >= Cout * NPX) return;
    int px = g & (NPX - 1);
    int oc = g >> 14;
    int y = px >> 7, x = px & 127;
    float acc = bias[oc];
    for (int ci = 0; ci < CC; ++ci) {
        const F8* ip = in + (size_t)ci * NPX;
        const float* wp = w + ((size_t)oc * CC + ci) * 9;
#pragma unroll
        for (int dy = 0; dy < 3; ++dy) {
            int yy = y + dy - 1;
            if (yy < 0 || yy >= HW) continue;
#pragma unroll
            for (int dxk = 0; dxk < 3; ++dxk) {
                int xx = x + dxk - 1;
                if (xx < 0 || xx >= HW) continue;
                acc += dec8(ip[yy * HW + xx]) * wp[dy * 3 + dxk];
            }
        }
    }
    out[g] = acc;
}

__global__ __launch_bounds__(256) void v9_align(
    const float* __restrict__ in, const float* __restrict__ bbox,
    const float* __restrict__ w, const float* __restrict__ bias,
    const int* __restrict__ stride_p, F8* __restrict__ out)
{
    const int y   = blockIdx.x;
    const int ocb = blockIdx.y * 64;
    const int tid = threadIdx.x;
    const int xg  = tid & 15;
    const int og  = tid >> 4;
    const int x0  = xg * 8;
    const int oc0 = ocb + og * 4;

    __shared__ float smp[9][128];
    __shared__ int   s_ix[1152], s_iy[1152];
    __shared__ float s_wx1[1152], s_wy1[1152];

    const float s = (float)(*stride_p);
    for (int t = tid; t < 1152; t += 256) {
        int k = t >> 7, xx = t & 127;
        int px = y * HW + xx;
        float gx, gy, gw, gh, ga;
        v9_decode_px(bbox, px, s, gx, gy, gw, gh, ga);
        float axc = gx / s, ayc = gy / s;
        float aw3 = gw / (s * 3.f), ah3 = gh / (s * 3.f);
        float cs = cosf(ga), sn = sinf(ga);
        float kx = (float)(k % 3 - 1), ky = (float)(k / 3 - 1);
        float ddx = aw3 * kx, ddy = ah3 * ky;
        float xf = cs * ddx - sn * ddy + axc;
        float yf = sn * ddx + cs * ddy + ayc;
        float fx = floorf(xf), fy = floorf(yf);
        s_ix[t]  = (int)fx;
        s_iy[t]  = (int)fy;
        s_wx1[t] = xf - fx;
        s_wy1[t] = yf - fy;
    }

    float acc[4][8];
#pragma unroll
    for (int i = 0; i < 4; ++i)
#pragma unroll
        for (int j = 0; j < 8; ++j) acc[i][j] = 0.f;

    for (int ci = 0; ci < CC; ++ci) {
        __syncthreads();
        const float* ip = in + (size_t)ci * NPX;
        for (int t = tid; t < 1152; t += 256) {
            int ix = s_ix[t], iy = s_iy[t];
            float wx1 = s_wx1[t], wx0 = 1.f - wx1;
            float wy1 = s_wy1[t], wy0 = 1.f - wy1;
            float v = 0.f;
            bool xv0 = (ix >= 0) && (ix < HW);
            bool xv1 = (ix + 1 >= 0) && (ix + 1 < HW);
            bool yv0 = (iy >= 0) && (iy < HW);
            bool yv1 = (iy + 1 >= 0) && (iy + 1 < HW);
            if (yv0 && xv0) v += ip[iy * HW + ix] * wy0 * wx0;
            if (yv0 && xv1) v += ip[iy * HW + ix + 1] * wy0 * wx1;
            if (yv1 && xv0) v += ip[(iy + 1) * HW + ix] * wy1 * wx0;
            if (yv1 && xv1) v += ip[(iy + 1) * HW + ix + 1] * wy1 * wx1;
            smp[t >> 7][t & 127] = v;
        }
        __syncthreads();

        float wv[4][9];
#pragma unroll
        for (int i = 0; i < 4; ++i) {
            const float* wp = w + ((size_t)(oc0 + i) * CC + ci) * 9;
#pragma unroll
            for (int k = 0; k < 9; ++k) wv[i][k] = wp[k];
        }
#pragma unroll
        for (int k = 0; k < 9; ++k) {
            float iv[8];
#pragma unroll
            for (int j = 0; j < 8; ++j) iv[j] = smp[k][x0 + j];
#pragma unroll
            for (int i = 0; i < 4; ++i)
#pragma unroll
                for (int j = 0; j < 8; ++j)
                    acc[i][j] += iv[j] * wv[i][k];
        }
    }
#pragma unroll
    for (int i = 0; i < 4; ++i) {
        float b = bias[oc0 + i];
#pragma unroll
        for (int j = 0; j < 8; ++j)
            out[(size_t)(oc0 + i) * NPX + y * HW + x0 + j].b =
                enc8(fmaxf(acc[i][j] + b, 0.f));
    }
}

__global__ __launch_bounds__(256) void v9_pool(
    const F8* __restrict__ orf, F8* __restrict__ pooled)
{
    int g = blockIdx.x * 256 + threadIdx.x;
    if (g >= 32 * NPX) return;
    int px = g & (NPX - 1);
    int c  = g >> 14;
    float m = -3.4e38f;
#pragma unroll
    for (int r = 0; r < 8; ++r)
        m = fmaxf(m, dec8(orf[(size_t)(c * 8 + r) * NPX + px]));
    pooled[g].b = enc8(m);
}

// ===========================================================================
extern "C" void kernel_launch(void* const* d_in, const int* in_sizes, int n_in,
                              void* d_out, int out_size, void* d_ws, size_t ws_size,
                              hipStream_t stream)
{
    const float* feats = (const float*)d_in[0];
    const float* frw0 = (const float*)d_in[1];  const float* frb0 = (const float*)d_in[2];
    const float* frw1 = (const float*)d_in[3];  const float* frb1 = (const float*)d_in[4];
    const float* frhw = (const float*)d_in[5];  const float* frhb = (const float*)d_in[6];
    const float* fcw0 = (const float*)d_in[7];  const float* fcb0 = (const float*)d_in[8];
    const float* fcw1 = (const float*)d_in[9];  const float* fcb1 = (const float*)d_in[10];
    const float* fchw = (const float*)d_in[11]; const float* fchb = (const float*)d_in[12];
    const float* alw  = (const float*)d_in[13]; const float* alb  = (const float*)d_in[14];
    const float* orw  = (const float*)d_in[15]; const float* orb  = (const float*)d_in[16];
    const float* drw0 = (const float*)d_in[17]; const float* drb0 = (const float*)d_in[18];
    const float* drw1 = (const float*)d_in[19]; const float* drb1 = (const float*)d_in[20];
    const float* drhw = (const float*)d_in[21]; const float* drhb = (const float*)d_in[22];
    const float* dcw0 = (const float*)d_in[23]; const float* dcb0 = (const float*)d_in[24];
    const float* dcw1 = (const float*)d_in[25]; const float* dcb1 = (const float*)d_in[26];
    const float* dchw = (const float*)d_in[27]; const float* dchb = (const float*)d_in[28];
    const int*  stride_p = (const int*)d_in[29];

    float* out = (float*)d_out;   // fp32 output (proven round 8/9)
    float* o_fam_cls  = out;
    float* o_fam_bbox = out + 245760;
    float* o_odm_cls  = out + 327680;
    float* o_odm_bbox = out + 573440;
    float* o_anchors  = out + 655360;
    float* o_refine   = out + 737280;

    dim3 blk(256), blk8(512);

    const size_t NEED3     = 55097344;   // paired-branch layout (5 act buffers)
    const size_t NEED2     = 38172672;   // fused-prep weight arena layout
    const size_t NEED_FAST = 27395072;
    const size_t NEED_V9   = 8912896;

    if (ws_size >= NEED3) {
        char* ws = (char*)d_ws;
        short* xt = (short*)(ws + 0);
        short* T0 = (short*)(ws + 8388608);
        short* T1 = (short*)(ws + 16777216);
        short* T2 = (short*)(ws + 25165824);
        short* T3 = (short*)(ws + 33554432);
        short* P  = (short*)(ws + 41943040);   // [16384][32]
        short* WA = (short*)(ws + 42991616);   // fused weight arena (11.94 MB)
        float* BA = (float*)(ws + 55083008);   // 14 x 256 fp32 biases

        v12_prepall<<<dim3(2304, 14), blk, 0, stream>>>(
            frw0, frw1, fcw0, fcw1, alw, orw, drw0, drw1, dcw1,
            frhw, fchw, drhw, dchw, dcw0,
            frb0, frb1, fcb0, fcb1, alb, orb, drb0, drb1, dcb1,
            frhb, fchb, drhb, dchb, dcb0,
            WA, BA);
        v10_transpose<<<dim3(512, 8), blk, 0, stream>>>(feats, xt);

        // FAM conv0 (reg + cls), conv1 (reg + cls) — 8-wave, 16 waves/CU
        v15_pair<1, 256, 256><<<dim3(256, 2), blk8, 0, stream>>>(
            xt, xt, WA + 0, WA + 1179648, BA + 0 * 256, BA + 2 * 256, T0, T2);
        v15_pair<1, 256, 256><<<dim3(256, 2), blk8, 0, stream>>>(
            T0, T2, WA + 589824, WA + 1769472, BA + 1 * 256, BA + 3 * 256, T1, T3);
        v13_pair<0, 1, 1, 256, 256, 1, 1, 64><<<dim3(256, 2), blk, 0, stream>>>(
            T1, T3, WA + 5308416, WA + 5455872, BA + 9 * 256, BA + 10 * 256,
            o_fam_bbox, o_fam_cls, 5, 15);
        // decode
        v9_decode<<<dim3(64), blk, 0, stream>>>(o_fam_bbox, o_anchors, o_refine, stride_p);
        // align conv -> T0
        v13_align<<<dim3(256, 2), blk, 0, stream>>>(xt, o_fam_bbox, WA + 2359296, BA + 4 * 256, stride_p, T0);
        // OR conv -> T1, no relu — 8-wave
        v15_conv<0, 256><<<dim3(256, 1), blk8, 0, stream>>>(T0, WA + 2949120, BA + 5 * 256, T1);
        // pool -> P
        v10_pool<<<dim3(2048), blk, 0, stream>>>(T1, P);
        // ODM conv0 (reg Cin=256 + cls Cin=32), conv1 (reg + cls), heads
        v15_pair<1, 256, 32><<<dim3(256, 2), blk8, 0, stream>>>(
            T1, P, WA + 3538944, WA + 5898240, BA + 6 * 256, BA + 13 * 256, T0, T2);
        v15_pair<1, 256, 256><<<dim3(256, 2), blk8, 0, stream>>>(
            T0, T2, WA + 4128768, WA + 4718592, BA + 7 * 256, BA + 8 * 256, T1, T3);
        v13_pair<0, 1, 0, 256, 256, 1, 1, 64><<<dim3(256, 2), blk, 0, stream>>>(
            T1, T3, WA + 5603328, WA + 5750784, BA + 11 * 256, BA + 12 * 256,
            o_odm_bbox, o_odm_cls, 5, 15);
    } else if (ws_size >= NEED2) {
        char* ws = (char*)d_ws;
        short* xt = (short*)(ws + 0);
        short* T0 = (short*)(ws + 8388608);
        short* T1 = (short*)(ws + 16777216);
        short* P  = (short*)(ws + 25165824);
        short* WA = (short*)(ws + 26214400);
        float* BA = (float*)(ws + 38158336);

        dim3 gc(256, 2), gh(256, 1);

        v12_prepall<<<dim3(2304, 14), blk, 0, stream>>>(
            frw0, frw1, fcw0, fcw1, alw, orw, drw0, drw1, dcw1,
            frhw, fchw, drhw, dchw, dcw0,
            frb0, frb1, fcb0, fcb1, alb, orb, drb0, drb1, dcb1,
            frhb, fchb, drhb, dchb, dcb0,
            WA, BA);
        v10_transpose<<<dim3(512, 8), blk, 0, stream>>>(feats, xt);

        v13_conv<1, 0, 0, 256, 2><<<gc, blk, 0, stream>>>(xt, WA + 0,       BA + 0 * 256, T0, 256, 256);
        v13_conv<1, 0, 0, 256, 2><<<gc, blk, 0, stream>>>(T0, WA + 589824,  BA + 1 * 256, T1, 256, 256);
        v13_conv<0, 1, 1, 256, 1><<<gh, blk, 0, stream>>>(T1, WA + 5308416, BA + 9 * 256, o_fam_bbox, 5, 64);
        v13_conv<1, 0, 0, 256, 2><<<gc, blk, 0, stream>>>(xt, WA + 1179648, BA + 2 * 256, T0, 256, 256);
        v13_conv<1, 0, 0, 256, 2><<<gc, blk, 0, stream>>>(T0, WA + 1769472, BA + 3 * 256, T1, 256, 256);
        v13_conv<0, 1, 1, 256, 1><<<gh, blk, 0, stream>>>(T1, WA + 5455872, BA + 10 * 256, o_fam_cls, 15, 64);
        v9_decode<<<dim3(64), blk, 0, stream>>>(o_fam_bbox, o_anchors, o_refine, stride_p);
        v13_align<<<dim3(256, 2), blk, 0, stream>>>(xt, o_fam_bbox, WA + 2359296, BA + 4 * 256, stride_p, T0);
        v13_conv<0, 0, 0, 256, 2><<<gc, blk, 0, stream>>>(T0, WA + 2949120, BA + 5 * 256, T1, 256, 256);
        v10_pool<<<dim3(2048), blk, 0, stream>>>(T1, P);
        v13_conv<1, 0, 0, 256, 2><<<gc, blk, 0, stream>>>(T1, WA + 3538944, BA + 6 * 256, T0, 256, 256);
        v13_conv<1, 0, 0, 256, 2><<<gc, blk, 0, stream>>>(T0, WA + 4128768, BA + 7 * 256, T1, 256, 256);
        v13_conv<0, 1, 0, 256, 1><<<gh, blk, 0, stream>>>(T1, WA + 5603328, BA + 11 * 256, o_odm_bbox, 5, 64);
        v13_conv<1, 0, 0, 32, 2><<<gc, blk, 0, stream>>>(P, WA + 5898240, BA + 13 * 256, T0, 256, 256);
        v13_conv<1, 0, 0, 256, 2><<<gc, blk, 0, stream>>>(T0, WA + 4718592, BA + 8 * 256, T1, 256, 256);
        v13_conv<0, 1, 0, 256, 1><<<gh, blk, 0, stream>>>(T1, WA + 5750784, BA + 12 * 256, o_odm_cls, 15, 64);
    } else if (ws_size >= NEED_FAST) {
        char* ws = (char*)d_ws;
        short* xt = (short*)(ws + 0);
        short* T0 = (short*)(ws + 8388608);
        short* T1 = (short*)(ws + 16777216);
        short* P  = (short*)(ws + 25165824);
        short* WB = (short*)(ws + 26214400);
        float* BB = (float*)(ws + 27394048);

        dim3 gc(256, 2), gh(256, 1);

        v10_transpose<<<dim3(512, 8), blk, 0, stream>>>(feats, xt);

#define PREP(W, B, COUT, CIN, OCP, MODE) \
        v10_prep<<<dim3((9 * (OCP) * (CIN) + 255) / 256), blk, 0, stream>>>( \
            W, B, WB, BB, COUT, CIN, OCP, MODE)

        PREP(frw0, frb0, 256, 256, 256, 0);
        v13_conv<1, 0, 0, 256, 2><<<gc, blk, 0, stream>>>(xt, WB, BB, T0, 256, 256);
        PREP(frw1, frb1, 256, 256, 256, 0);
        v13_conv<1, 0, 0, 256, 2><<<gc, blk, 0, stream>>>(T0, WB, BB, T1, 256, 256);
        PREP(frhw, frhb, 5, 256, 64, 2);
        v13_conv<0, 1, 1, 256, 1><<<gh, blk, 0, stream>>>(T1, WB, BB, o_fam_bbox, 5, 64);
        PREP(fcw0, fcb0, 256, 256, 256, 0);
        v13_conv<1, 0, 0, 256, 2><<<gc, blk, 0, stream>>>(xt, WB, BB, T0, 256, 256);
        PREP(fcw1, fcb1, 256, 256, 256, 0);
        v13_conv<1, 0, 0, 256, 2><<<gc, blk, 0, stream>>>(T0, WB, BB, T1, 256, 256);
        PREP(fchw, fchb, 15, 256, 64, 2);
        v13_conv<0, 1, 1, 256, 1><<<gh, blk, 0, stream>>>(T1, WB, BB, o_fam_cls, 15, 64);
        v9_decode<<<dim3(64), blk, 0, stream>>>(o_fam_bbox, o_anchors, o_refine, stride_p);
        PREP(alw, alb, 256, 256, 256, 0);
        v13_align<<<dim3(256, 2), blk, 0, stream>>>(xt, o_fam_bbox, WB, BB, stride_p, T0);
        PREP(orw, orb, 256, 256, 256, 1);
        v13_conv<0, 0, 0, 256, 2><<<gc, blk, 0, stream>>>(T0, WB, BB, T1, 256, 256);
        v10_pool<<<dim3(2048), blk, 0, stream>>>(T1, P);
        PREP(drw0, drb0, 256, 256, 256, 0);
        v13_conv<1, 0, 0, 256, 2><<<gc, blk, 0, stream>>>(T1, WB, BB, T0, 256, 256);
        PREP(drw1, drb1, 256, 256, 256, 0);
        v13_conv<1, 0, 0, 256, 2><<<gc, blk, 0, stream>>>(T0, WB, BB, T1, 256, 256);
        PREP(drhw, drhb, 5, 256, 64, 0);
        v13_conv<0, 1, 0, 256, 1><<<gh, blk, 0, stream>>>(T1, WB, BB, o_odm_bbox, 5, 64);
        PREP(dcw0, dcb0, 256, 32, 256, 0);
        v13_conv<1, 0, 0, 32, 2><<<gc, blk, 0, stream>>>(P, WB, BB, T0, 256, 256);
        PREP(dcw1, dcb1, 256, 256, 256, 0);
        v13_conv<1, 0, 0, 256, 2><<<gc, blk, 0, stream>>>(T0, WB, BB, T1, 256, 256);
        PREP(dchw, dchb, 15, 256, 64, 0);
        v13_conv<0, 1, 0, 256, 1><<<gh, blk, 0, stream>>>(T1, WB, BB, o_odm_cls, 15, 64);
#undef PREP
    } else if (ws_size >= NEED_V9) {
        // -------- verbatim round-9 passing path --------
        F8* A = (F8*)d_ws;
        F8* B = (F8*)((char*)d_ws + 4194304);
        F8* P = (F8*)((char*)d_ws + 8388608);
        dim3 gconv(128, 4);

        v9_conv3x3<float, 1, 0><<<gconv, blk, 0, stream>>>(feats, frw0, frb0, A, 256);
        v9_conv3x3<F8,    1, 0><<<gconv, blk, 0, stream>>>(A, frw1, frb1, B, 256);
        v9_head1x1<<<dim3(5 * 64), blk, 0, stream>>>(B, frhw, frhb, o_fam_bbox, 5);
        v9_conv3x3<float, 1, 0><<<gconv, blk, 0, stream>>>(feats, fcw0, fcb0, A, 256);
        v9_conv3x3<F8,    1, 0><<<gconv, blk, 0, stream>>>(A, fcw1, fcb1, B, 256);
        v9_head1x1<<<dim3(15 * 64), blk, 0, stream>>>(B, fchw, fchb, o_fam_cls, 15);
        v9_decode<<<dim3(64), blk, 0, stream>>>(o_fam_bbox, o_anchors, o_refine, stride_p);
        v9_align<<<gconv, blk, 0, stream>>>(feats, o_fam_bbox, alw, alb, stride_p, A);
        v9_conv3x3<F8, 0, 1><<<gconv, blk, 0, stream>>>(A, orw, orb, B, 256);
        v9_pool<<<dim3(2048), blk, 0, stream>>>(B, P);
        v9_conv3x3<F8, 1, 0><<<gconv, blk, 0, stream>>>(B, drw0, drb0, A, 256);
        v9_conv3x3<F8, 1, 0><<<gconv, blk, 0, stream>>>(A, drw1, drb1, B, 256);
        v9_head3x3<<<dim3(5 * 64), blk, 0, stream>>>(B, drhw, drhb, o_odm_bbox, 5);
        v9_conv3x3<F8, 1, 0><<<gconv, blk, 0, stream>>>(P, dcw0, dcb0, A, 32);
        v9_conv3x3<F8, 1, 0><<<gconv, blk, 0, stream>>>(A, dcw1, dcb1, B, 256);
        v9_head3x3<<<dim3(15 * 64), blk, 0, stream>>>(B, dchw, dchb, o_odm_cls, 15);
    }
}

// Round 17
// 538.762 us; speedup vs baseline: 1.0066x; 1.0066x over previous
//
#include <hip/hip_runtime.h>
#include <hip/hip_bf16.h>
#include <hip/hip_fp16.h>

#define HW 128
#define NPX 16384
#define CC 256

typedef short  bf16x8  __attribute__((ext_vector_type(8)));
typedef short  short4v __attribute__((ext_vector_type(4)));
typedef float  f32x4   __attribute__((ext_vector_type(4)));
typedef unsigned int u32x4 __attribute__((ext_vector_type(4)));

// ---- scalar bf16 bit helpers (RNE) ----
static __device__ __forceinline__ short f2bs(float v) {
    union { float f; unsigned u; } x; x.f = v;
    unsigned r = x.u + 0x7FFFu + ((x.u >> 16) & 1u);
    return (short)(r >> 16);
}
static __device__ __forceinline__ float bs2f(short s) {
    union { unsigned u; float f; } x; x.u = ((unsigned)(unsigned short)s) << 16;
    return x.f;
}

// XCD-locality swizzle for gridDim.x==256: 32 consecutive logical blocks
// (16 adjacent image rows) land on one XCD -> halo rows hit that XCD's L2.
// Verified round 5: FETCH 30MB -> 13.9MB on the big convs.
static __device__ __forceinline__ int bx_swz() {
    return ((blockIdx.x & 7) << 5) | (blockIdx.x >> 3);
}

// fp8 e5m2 (v9 fallback path)
struct F8 { unsigned char b; };
__device__ __forceinline__ unsigned char enc8(float v) {
    unsigned short u = __half_as_ushort(__float2half(v));
    unsigned short s = u & 0x8000, mag = u & 0x7FFF;
    mag = (unsigned short)(mag + 0x0080);
    return (unsigned char)((unsigned short)(s | mag) >> 8);
}
__device__ __forceinline__ float dec8(F8 v) {
    return __half2float(__ushort_as_half((unsigned short)(v.b) << 8));
}
__device__ __forceinline__ float ldg_(const float* p) { return *p; }
__device__ __forceinline__ float ldg_(const F8* p)    { return dec8(*p); }

// ORConv rotation: c_ROT[r][k] = RING[(INV[k]-r)&7], RING={0,1,2,5,8,7,6,3}.
__constant__ int c_ROT9[8][9] = {
    {0,1,2,3,4,5,6,7,8},
    {3,0,1,6,4,2,7,8,5},
    {6,3,0,7,4,1,8,5,2},
    {7,6,3,8,4,0,5,2,1},
    {8,7,6,5,4,3,2,1,0},
    {5,8,7,2,4,6,1,0,3},
    {2,5,8,1,4,7,0,3,6},
    {1,2,5,0,4,8,3,6,7},
};

// decode helper: fam_bbox fp32 [5,NPX] + px -> refined rotated box (fp32)
__device__ __forceinline__ void v9_decode_px(
    const float* bbox, int px, float s,
    float& gx, float& gy, float& gw, float& gh, float& ga)
{
    int y = px >> 7, x = px & 127;
    float ax = x * s + 3.5f, ay = y * s + 3.5f;
    float dx = bbox[0 * NPX + px];
    float dy = bbox[1 * NPX + px];
    float dw = bbox[2 * NPX + px];
    float dh = bbox[3 * NPX + px];
    float dt = bbox[4 * NPX + px];
    const float maxr = 13.815510558f;
    dw = fminf(fmaxf(dw, -maxr), maxr);
    dh = fminf(fmaxf(dh, -maxr), maxr);
    gx = dx * 32.f + ax;
    gy = dy * 32.f + ay;
    gw = 32.f * expf(dw);
    gh = 32.f * expf(dh);
    const float PI = 3.14159265358979323846f;
    float m = fmodf(dt + PI * 0.25f, PI);
    if (m < 0.f) m += PI;
    ga = m - PI * 0.25f;
}

// ===========================================================================
// ============================  FINAL FAST PATH  ============================
// Terminal build (7 confirmations, 540-546us band; best 540.1us round 12).
// 8-wave 512-thread conv blocks (16 waves/CU), per-tap A-prefetch,
// async-stage split, XCD swizzle, fused single-launch weight prep, paired
// FAM/ODM branches, depth-2 gather-pipe align. Parameter space mapped
// rounds 3-11: conv-pair floor ~81us across every ILP/TLP/occupancy/
// MFMA-shape knob (regalloc vetoes all full-ILP 16-wave variants; 32x32
// MFMA compiles worse). Round-16 analysis closed the LDS-stride lever:
// stride 40 shorts -> 16B-slot coefficient 5 (coprime 8) => b128 reads are
// uniform 8 lanes/slot = the 8-cycle minimum; the 5.12M BANK_CONFLICT
// counter is counted-but-free 2-way write aliasing (m136). All 16B-aligned
// alternatives (48/56/72) are same-or-worse class. Plateau is the
// barrier-drain structure, escapable only via inline-asm counted-vmcnt
// K-loop — out of this session's scope. Locked.
// ===========================================================================

// feats [256][16384] fp32 -> xt [16384][256] bf16 (LDS 32x32 tile transpose)
__global__ __launch_bounds__(256) void v10_transpose(
    const float* __restrict__ f, short* __restrict__ xt)
{
    __shared__ float tile[32][33];
    int px0 = blockIdx.x * 32, ci0 = blockIdx.y * 32;
    int tx = threadIdx.x & 31, ty = threadIdx.x >> 5;
#pragma unroll
    for (int i = 0; i < 4; ++i) {
        int ci = ty + i * 8;
        tile[ci][tx] = f[(size_t)(ci0 + ci) * NPX + px0 + tx];
    }
    __syncthreads();
#pragma unroll
    for (int i = 0; i < 4; ++i) {
        int pxr = ty + i * 8;
        xt[(size_t)(px0 + pxr) * 256 + ci0 + tx] = f2bs(tile[tx][pxr]);
    }
}

// weight prep -> wb[t][ocp][ci] bf16 (+ padded bias bb[ocp] fp32)
__global__ __launch_bounds__(256) void v10_prep(
    const float* __restrict__ w, const float* __restrict__ bias,
    short* __restrict__ wb, float* __restrict__ bb,
    int Cout, int Cin, int OCP, int mode)
{
    int g = blockIdx.x * 256 + threadIdx.x;
    if (g < OCP) bb[g] = (g < Cout) ? ((mode == 1) ? bias[g >> 3] : bias[g]) : 0.f;
    int tot = 9 * OCP * Cin;
    if (g >= tot) return;
    int t   = g / (OCP * Cin);
    int rem = g - t * OCP * Cin;
    int oc  = rem / Cin;
    int ci  = rem - oc * Cin;
    float v = 0.f;
    if (oc < Cout) {
        if (mode == 0)      v = w[((size_t)oc * Cin + ci) * 9 + t];
        else if (mode == 1) { int o = oc >> 3, r = oc & 7;
                              v = w[((size_t)o * Cin + ci) * 9 + c_ROT9[r][t]]; }
        else if (t == 4)    v = w[(size_t)oc * Cin + ci];
    }
    wb[g] = f2bs(v);
}

// fused prep: job table. {dst_off(shorts), Cout, Cin, OCP, mode}
__constant__ int c_JOB[14][5] = {
    {0,       256, 256, 256, 0},  //  0 frw0
    {589824,  256, 256, 256, 0},  //  1 frw1
    {1179648, 256, 256, 256, 0},  //  2 fcw0
    {1769472, 256, 256, 256, 0},  //  3 fcw1
    {2359296, 256, 256, 256, 0},  //  4 alw
    {2949120, 256, 256, 256, 1},  //  5 orw
    {3538944, 256, 256, 256, 0},  //  6 drw0
    {4128768, 256, 256, 256, 0},  //  7 drw1
    {4718592, 256, 256, 256, 0},  //  8 dcw1
    {5308416, 5,   256, 64,  2},  //  9 frhw
    {5455872, 15,  256, 64,  2},  // 10 fchw
    {5603328, 5,   256, 64,  0},  // 11 drhw (3x3 head)
    {5750784, 15,  256, 64,  0},  // 12 dchw (3x3 head)
    {5898240, 256, 32,  256, 0},  // 13 dcw0
};

__global__ __launch_bounds__(256) void v12_prepall(
    const float* w0, const float* w1, const float* w2, const float* w3,
    const float* w4, const float* w5, const float* w6, const float* w7,
    const float* w8, const float* w9, const float* w10, const float* w11,
    const float* w12, const float* w13,
    const float* b0, const float* b1, const float* b2, const float* b3,
    const float* b4, const float* b5, const float* b6, const float* b7,
    const float* b8, const float* b9, const float* b10, const float* b11,
    const float* b12, const float* b13,
    short* __restrict__ wball, float* __restrict__ bball)
{
    const float* ws_[14] = {w0,w1,w2,w3,w4,w5,w6,w7,w8,w9,w10,w11,w12,w13};
    const float* bs_[14] = {b0,b1,b2,b3,b4,b5,b6,b7,b8,b9,b10,b11,b12,b13};
    const int j = blockIdx.y;
    const int dst  = c_JOB[j][0];
    const int Cout = c_JOB[j][1];
    const int Cin  = c_JOB[j][2];
    const int OCP  = c_JOB[j][3];
    const int mode = c_JOB[j][4];
    const float* w = ws_[j];
    const float* bias = bs_[j];
    int g = blockIdx.x * 256 + threadIdx.x;
    if (g < OCP) bball[j * 256 + g] = (g < Cout) ? ((mode == 1) ? bias[g >> 3] : bias[g]) : 0.f;
    int tot = 9 * OCP * Cin;
    if (g >= tot) return;
    int t   = g / (OCP * Cin);
    int rem = g - t * OCP * Cin;
    int oc  = rem / Cin;
    int ci  = rem - oc * Cin;
    float v = 0.f;
    if (oc < Cout) {
        if (mode == 0)      v = w[((size_t)oc * Cin + ci) * 9 + t];
        else if (mode == 1) { int o = oc >> 3, r = oc & 7;
                              v = w[((size_t)o * Cin + ci) * 9 + c_ROT9[r][t]]; }
        else if (t == 4)    v = w[(size_t)oc * Cin + ci];
    }
    wball[dst + g] = f2bs(v);
}

// ---------------------------------------------------------------------------
// OCG=2 conv body (proven round 3/5; kept for heads + fallback tiers)
template <int RELU, int HEAD, int ONLY1, int CIN, int OCG>
__device__ __forceinline__ void conv_body(
    short* S,   // [2][7920] shorts
    const short* __restrict__ xin, const short* __restrict__ wb,
    const float* __restrict__ bb, void* __restrict__ outv,
    int CoutAct, int OCP, int bx, int oy)
{
    const int y    = bx >> 1;
    const int xh   = (bx & 1) * 64;
    const int ocb  = oy * 64 * OCG;
    const int tid  = threadIdx.x;
    const int wv   = tid >> 6;
    const int lane = tid & 63;
    const int quad = lane >> 4;
    const int l15  = lane & 15;
    const int ocw  = ocb + wv * 16 * OCG;

    int gofs[4], lofs[4];
#pragma unroll
    for (int i = 0; i < 4; ++i) {
        int e = tid + i * 256;
        gofs[i] = -1; lofs[i] = -1;
        if (e < 792) {
            int pos = e >> 2, part = e & 3;
            int r = pos / 66, c = pos - r * 66;
            int yy = y - 1 + r, xx = xh - 1 + c;
            lofs[i] = (r * 66 + c) * 40 + part * 8;
            if (yy >= 0 && yy < HW && xx >= 0 && xx < HW)
                gofs[i] = (yy * HW + xx) * CIN + part * 8;
        }
    }
    const bf16x8 zf = (bf16x8){0, 0, 0, 0, 0, 0, 0, 0};

    f32x4 acc[4][OCG];
#pragma unroll
    for (int p = 0; p < 4; ++p)
#pragma unroll
        for (int g = 0; g < OCG; ++g) acc[p][g] = (f32x4){0.f, 0.f, 0.f, 0.f};

    {
        bf16x8 st[4];
#pragma unroll
        for (int i = 0; i < 4; ++i) {
            st[i] = zf;
            if (gofs[i] >= 0) st[i] = *(const bf16x8*)(xin + gofs[i]);
        }
#pragma unroll
        for (int i = 0; i < 4; ++i)
            if (lofs[i] >= 0) *(bf16x8*)(&S[lofs[i]]) = st[i];
    }
    bf16x8 a[9][OCG];
#pragma unroll
    for (int t = (ONLY1 ? 4 : 0); t < (ONLY1 ? 5 : 9); ++t)
#pragma unroll
        for (int g = 0; g < OCG; ++g)
            a[t][g] = *(const bf16x8*)(wb +
                ((size_t)(t * OCP + ocw + g * 16 + l15) * CIN + quad * 8));
    __syncthreads();

    const int NST = CIN / 32;
    int cur = 0;
    for (int s = 0; s < NST; ++s) {
        const int cib = s * 32;

        bf16x8 st[4];
        if (s + 1 < NST) {
#pragma unroll
            for (int i = 0; i < 4; ++i) {
                st[i] = zf;
                if (gofs[i] >= 0)
                    st[i] = *(const bf16x8*)(xin + gofs[i] + cib + 32);
            }
        }

#pragma unroll
        for (int t = (ONLY1 ? 4 : 0); t < (ONLY1 ? 5 : 9); ++t) {
            const int r = t / 3, dxk = t % 3 - 1;
#pragma unroll
            for (int p = 0; p < 4; ++p) {
                int c = 1 + p * 16 + l15 + dxk;
                bf16x8 b = *(const bf16x8*)(&S[cur * 7920 + (r * 66 + c) * 40 + quad * 8]);
#pragma unroll
                for (int g = 0; g < OCG; ++g)
                    acc[p][g] = __builtin_amdgcn_mfma_f32_16x16x32_bf16(a[t][g], b, acc[p][g], 0, 0, 0);
            }
            if (s + 1 < NST) {
#pragma unroll
                for (int g = 0; g < OCG; ++g)
                    a[t][g] = *(const bf16x8*)(wb +
                        ((size_t)(t * OCP + ocw + g * 16 + l15) * CIN + cib + 32 + quad * 8));
            }
        }

        if (s + 1 < NST) {
#pragma unroll
            for (int i = 0; i < 4; ++i)
                if (lofs[i] >= 0) *(bf16x8*)(&S[(cur ^ 1) * 7920 + lofs[i]]) = st[i];
        }
        __syncthreads();
        cur ^= 1;
    }

#pragma unroll
    for (int p = 0; p < 4; ++p) {
        const int px = y * HW + xh + p * 16 + l15;
#pragma unroll
        for (int g = 0; g < OCG; ++g) {
            const int ocq = ocw + g * 16 + quad * 4;
            if (HEAD) {
                float* o = (float*)outv;
#pragma unroll
                for (int r = 0; r < 4; ++r)
                    if (ocq + r < CoutAct)
                        o[(size_t)(ocq + r) * NPX + px] = acc[p][g][r] + bb[ocq + r];
            } else {
                short4v s4;
#pragma unroll
                for (int r = 0; r < 4; ++r) {
                    float v = acc[p][g][r] + bb[ocq + r];
                    if (RELU) v = fmaxf(v, 0.f);
                    s4[r] = f2bs(v);
                }
                *(short4v*)((short*)outv + (size_t)px * 256 + ocq) = s4;
            }
        }
    }
}

// ---------------------------------------------------------------------------
// 8-wave conv body (512 threads): 64 px x 256 oc per block, each wave owns
// 32 oc. Per tap: 4 b-frag reads feed 8 MFMAs; aC[2]/aN[2] per-tap
// A-prefetch. 2 blocks/CU -> 16 waves/CU (4/SIMD).
template <int RELU, int CIN>
__device__ __forceinline__ void conv_body8(
    short* S,   // [2][7920] shorts
    const short* __restrict__ xin, const short* __restrict__ wb,
    const float* __restrict__ bb, short* __restrict__ outb, int bx)
{
    const int y    = bx >> 1;
    const int xh   = (bx & 1) * 64;
    const int tid  = threadIdx.x;       // 0..511
    const int wv   = tid >> 6;          // 0..7
    const int lane = tid & 63;
    const int quad = lane >> 4;
    const int l15  = lane & 15;
    const int ocw  = wv * 32;

    // staging: 792 chunks over 512 threads (2 rounds)
    int gofs[2], lofs[2];
#pragma unroll
    for (int i = 0; i < 2; ++i) {
        int e = tid + i * 512;
        gofs[i] = -1; lofs[i] = -1;
        if (e < 792) {
            int pos = e >> 2, part = e & 3;
            int r = pos / 66, c = pos - r * 66;
            int yy = y - 1 + r, xx = xh - 1 + c;
            lofs[i] = (r * 66 + c) * 40 + part * 8;
            if (yy >= 0 && yy < HW && xx >= 0 && xx < HW)
                gofs[i] = (yy * HW + xx) * CIN + part * 8;
        }
    }
    const bf16x8 zf = (bf16x8){0, 0, 0, 0, 0, 0, 0, 0};

    f32x4 acc[4][2];
#pragma unroll
    for (int p = 0; p < 4; ++p) {
        acc[p][0] = (f32x4){0.f, 0.f, 0.f, 0.f};
        acc[p][1] = (f32x4){0.f, 0.f, 0.f, 0.f};
    }

    // prologue: stage slice 0; load A for (t=0, cib=0)
    {
        bf16x8 st[2];
#pragma unroll
        for (int i = 0; i < 2; ++i) {
            st[i] = zf;
            if (gofs[i] >= 0) st[i] = *(const bf16x8*)(xin + gofs[i]);
        }
#pragma unroll
        for (int i = 0; i < 2; ++i)
            if (lofs[i] >= 0) *(bf16x8*)(&S[lofs[i]]) = st[i];
    }
    bf16x8 aC[2], aN[2];
#pragma unroll
    for (int g = 0; g < 2; ++g)
        aC[g] = *(const bf16x8*)(wb +
            ((size_t)(ocw + g * 16 + l15) * CIN + quad * 8));
    aN[0] = aC[0]; aN[1] = aC[1];
    __syncthreads();

    const int NST = CIN / 32;
    int cur = 0;
    for (int s = 0; s < NST; ++s) {
        const int cib = s * 32;

        // issue next-slice staging loads (hide under MFMA phase)
        bf16x8 st[2];
        if (s + 1 < NST) {
#pragma unroll
            for (int i = 0; i < 2; ++i) {
                st[i] = zf;
                if (gofs[i] >= 0)
                    st[i] = *(const bf16x8*)(xin + gofs[i] + cib + 32);
            }
        }

#pragma unroll
        for (int t = 0; t < 9; ++t) {
            // prefetch A for next (tap, slice)
            const int nt   = (t == 8) ? 0 : t + 1;
            const int ncib = (t == 8) ? cib + 32 : cib;
            if (!(s == NST - 1 && t == 8)) {
#pragma unroll
                for (int g = 0; g < 2; ++g)
                    aN[g] = *(const bf16x8*)(wb +
                        ((size_t)(nt * 256 + ocw + g * 16 + l15) * CIN + ncib + quad * 8));
            }
            const int r = t / 3, dxk = t % 3 - 1;
#pragma unroll
            for (int p = 0; p < 4; ++p) {
                int c = 1 + p * 16 + l15 + dxk;
                bf16x8 b = *(const bf16x8*)(&S[cur * 7920 + (r * 66 + c) * 40 + quad * 8]);
                acc[p][0] = __builtin_amdgcn_mfma_f32_16x16x32_bf16(aC[0], b, acc[p][0], 0, 0, 0);
                acc[p][1] = __builtin_amdgcn_mfma_f32_16x16x32_bf16(aC[1], b, acc[p][1], 0, 0, 0);
            }
            aC[0] = aN[0]; aC[1] = aN[1];
        }

        if (s + 1 < NST) {
#pragma unroll
            for (int i = 0; i < 2; ++i)
                if (lofs[i] >= 0) *(bf16x8*)(&S[(cur ^ 1) * 7920 + lofs[i]]) = st[i];
        }
        __syncthreads();
        cur ^= 1;
    }

#pragma unroll
    for (int p = 0; p < 4; ++p) {
        const int px = y * HW + xh + p * 16 + l15;
#pragma unroll
        for (int g = 0; g < 2; ++g) {
            const int ocq = ocw + g * 16 + quad * 4;
            short4v s4;
#pragma unroll
            for (int r = 0; r < 4; ++r) {
                float v = acc[p][g][r] + bb[ocq + r];
                if (RELU) v = fmaxf(v, 0.f);
                s4[r] = f2bs(v);
            }
            *(short4v*)(outb + (size_t)px * 256 + ocq) = s4;
        }
    }
}

// single-branch conv kernel (OCG=2, fallback tiers)
template <int RELU, int HEAD, int ONLY1, int CIN, int OCG>
__global__ __launch_bounds__(256) void v13_conv(
    const short* __restrict__ xin, const short* __restrict__ wb,
    const float* __restrict__ bb, void* __restrict__ outv,
    int CoutAct, int OCP)
{
    __shared__ short S[2 * 7920];
    conv_body<RELU, HEAD, ONLY1, CIN, OCG>(S, xin, wb, bb, outv,
                                           CoutAct, OCP, bx_swz(), blockIdx.y);
}

// paired conv kernel (heads)
template <int RELU, int HEAD, int ONLY1, int CIN0, int CIN1, int OCG, int NY, int OCP>
__global__ __launch_bounds__(256) void v13_pair(
    const short* __restrict__ in0, const short* __restrict__ in1,
    const short* __restrict__ wb0, const short* __restrict__ wb1,
    const float* __restrict__ bb0, const float* __restrict__ bb1,
    void* __restrict__ out0, void* __restrict__ out1,
    int cout0, int cout1)
{
    __shared__ short S[2 * 7920];
    const int ybr = blockIdx.y;
    if (ybr < NY)
        conv_body<RELU, HEAD, ONLY1, CIN0, OCG>(S, in0, wb0, bb0, out0,
                                                cout0, OCP, bx_swz(), ybr);
    else
        conv_body<RELU, HEAD, ONLY1, CIN1, OCG>(S, in1, wb1, bb1, out1,
                                                cout1, OCP, bx_swz(), ybr - NY);
}

// 8-wave kernels (round-8/12 best config: waves_per_eu(4) min-bound).
template <int RELU, int CIN>
__global__ __launch_bounds__(512) __attribute__((amdgpu_waves_per_eu(4)))
void v15_conv(
    const short* __restrict__ xin, const short* __restrict__ wb,
    const float* __restrict__ bb, short* __restrict__ outb)
{
    __shared__ short S[2 * 7920];
    conv_body8<RELU, CIN>(S, xin, wb, bb, outb, bx_swz());
}

template <int RELU, int CIN0, int CIN1>
__global__ __launch_bounds__(512) __attribute__((amdgpu_waves_per_eu(4)))
void v15_pair(
    const short* __restrict__ in0, const short* __restrict__ in1,
    const short* __restrict__ wb0, const short* __restrict__ wb1,
    const float* __restrict__ bb0, const float* __restrict__ bb1,
    short* __restrict__ out0, short* __restrict__ out1)
{
    __shared__ short S[2 * 7920];
    if (blockIdx.y == 0)
        conv_body8<RELU, CIN0>(S, in0, wb0, bb0, out0, bx_swz());
    else
        conv_body8<RELU, CIN1>(S, in1, wb1, bb1, out1, bx_swz());
}

// -------- v13 align: deformable 3x3 conv via MFMA, depth-2 gather pipe ----
__global__ __launch_bounds__(256) void v13_align(
    const short* __restrict__ xt, const float* __restrict__ bbox,
    const short* __restrict__ wb, const float* __restrict__ bb,
    const int* __restrict__ stride_p, short* __restrict__ outa)
{
    const int bx   = bx_swz();
    const int y    = bx >> 1;
    const int xh   = (bx & 1) * 64;
    const int ocb  = blockIdx.y * 128;
    const int tid  = threadIdx.x;
    const int wv   = tid >> 6, lane = tid & 63, quad = lane >> 4, l15 = lane & 15;
    const int ocw  = ocb + wv * 32;

    __shared__ int   s_idx[4][576];
    __shared__ float s_wgt[4][576];
    __shared__ short S[2][64 * 40];

    const float s = (float)(*stride_p);
    for (int e = tid; e < 576; e += 256) {
        int t = e >> 6, xi = e & 63;
        int px = y * HW + xh + xi;
        float gx, gy, gw, gh, ga;
        v9_decode_px(bbox, px, s, gx, gy, gw, gh, ga);
        float axc = gx / s, ayc = gy / s;
        float aw3 = gw / (3.f * s), ah3 = gh / (3.f * s);
        float cs = cosf(ga), sn = sinf(ga);
        float kx = (float)(t % 3 - 1), ky = (float)(t / 3 - 1);
        float ddx = aw3 * kx, ddy = ah3 * ky;
        float xf = cs * ddx - sn * ddy + axc;
        float yf = sn * ddx + cs * ddy + ayc;
        float fx = floorf(xf), fy = floorf(yf);
        int ix = (int)fx, iy = (int)fy;
        float wx1 = xf - fx, wx0 = 1.f - wx1;
        float wy1 = yf - fy, wy0 = 1.f - wy1;
        bool x0v = (ix >= 0) && (ix < HW), x1v = (ix + 1 >= 0) && (ix + 1 < HW);
        bool y0v = (iy >= 0) && (iy < HW), y1v = (iy + 1 >= 0) && (iy + 1 < HW);
        int x0c = min(max(ix, 0), HW - 1), x1c = min(max(ix + 1, 0), HW - 1);
        int y0c = min(max(iy, 0), HW - 1), y1c = min(max(iy + 1, 0), HW - 1);
        s_idx[0][e] = y0c * HW + x0c;
        s_idx[1][e] = y0c * HW + x1c;
        s_idx[2][e] = y1c * HW + x0c;
        s_idx[3][e] = y1c * HW + x1c;
        s_wgt[0][e] = (y0v && x0v) ? wy0 * wx0 : 0.f;
        s_wgt[1][e] = (y0v && x1v) ? wy0 * wx1 : 0.f;
        s_wgt[2][e] = (y1v && x0v) ? wy1 * wx0 : 0.f;
        s_wgt[3][e] = (y1v && x1v) ? wy1 * wx1 : 0.f;
    }

    f32x4 acc[4][2];
#pragma unroll
    for (int p = 0; p < 4; ++p) { acc[p][0] = (f32x4){0,0,0,0}; acc[p][1] = (f32x4){0,0,0,0}; }

    const int spx = tid >> 2;
    const int sq  = tid & 3;
    const int sw  = spx * 40 + sq * 8;
    const bf16x8 zf = (bf16x8){0, 0, 0, 0, 0, 0, 0, 0};

    __syncthreads();

    bf16x8 aC0, aC1;
    bf16x8 gN0, gN1, gN2, gN3;
    float  wN0, wN1, wN2, wN3;
    {
        int e = spx;
        int i0 = s_idx[0][e], i1 = s_idx[1][e], i2 = s_idx[2][e], i3 = s_idx[3][e];
        float w0 = s_wgt[0][e], w1 = s_wgt[1][e], w2 = s_wgt[2][e], w3 = s_wgt[3][e];
        const short* base = xt + sq * 8;
        bf16x8 g0 = *(const bf16x8*)(base + (size_t)i0 * 256);
        bf16x8 g1 = *(const bf16x8*)(base + (size_t)i1 * 256);
        bf16x8 g2 = *(const bf16x8*)(base + (size_t)i2 * 256);
        bf16x8 g3 = *(const bf16x8*)(base + (size_t)i3 * 256);
        float v[8];
#pragma unroll
        for (int i = 0; i < 8; ++i)
            v[i] = w0 * bs2f(g0[i]) + w1 * bs2f(g1[i]) + w2 * bs2f(g2[i]) + w3 * bs2f(g3[i]);
        u32x4 r;
#pragma unroll
        for (int i = 0; i < 4; ++i)
            asm("v_cvt_pk_bf16_f32 %0, %1, %2" : "=v"(r[i]) : "v"(v[2 * i]), "v"(v[2 * i + 1]));
        *(u32x4*)(&S[0][sw]) = r;
    }
    {
        int e = 64 + spx;
        int i0 = s_idx[0][e], i1 = s_idx[1][e], i2 = s_idx[2][e], i3 = s_idx[3][e];
        wN0 = s_wgt[0][e]; wN1 = s_wgt[1][e]; wN2 = s_wgt[2][e]; wN3 = s_wgt[3][e];
        const short* base = xt + sq * 8;
        gN0 = *(const bf16x8*)(base + (size_t)i0 * 256);
        gN1 = *(const bf16x8*)(base + (size_t)i1 * 256);
        gN2 = *(const bf16x8*)(base + (size_t)i2 * 256);
        gN3 = *(const bf16x8*)(base + (size_t)i3 * 256);
    }
    aC0 = *(const bf16x8*)(wb + ((size_t)(ocw + l15) * 256 + quad * 8));
    aC1 = *(const bf16x8*)(wb + ((size_t)(ocw + 16 + l15) * 256 + quad * 8));
    __syncthreads();

    int cur = 0;
    for (int cib = 0; cib < 256; cib += 32) {
        for (int t = 0; t < 9; ++t) {
            const bool have1 = !(cib == 224 && t == 8);
            const bool have2 = !(cib == 224 && t >= 7);
            const int t1 = (t == 8) ? 0 : t + 1;
            const int c1 = (t == 8) ? cib + 32 : cib;
            int t2 = t + 2, c2 = cib;
            if (t2 > 8) { t2 -= 9; c2 += 32; }

            bf16x8 gF0 = zf, gF1 = zf, gF2 = zf, gF3 = zf;
            float  wF0 = 0.f, wF1 = 0.f, wF2 = 0.f, wF3 = 0.f;
            if (have2) {
                int e = t2 * 64 + spx;
                int i0 = s_idx[0][e], i1 = s_idx[1][e], i2 = s_idx[2][e], i3 = s_idx[3][e];
                wF0 = s_wgt[0][e]; wF1 = s_wgt[1][e]; wF2 = s_wgt[2][e]; wF3 = s_wgt[3][e];
                const short* base = xt + c2 + sq * 8;
                gF0 = *(const bf16x8*)(base + (size_t)i0 * 256);
                gF1 = *(const bf16x8*)(base + (size_t)i1 * 256);
                gF2 = *(const bf16x8*)(base + (size_t)i2 * 256);
                gF3 = *(const bf16x8*)(base + (size_t)i3 * 256);
            }
            bf16x8 aN0 = aC0, aN1 = aC1;
            if (have1) {
                aN0 = *(const bf16x8*)(wb + ((size_t)(t1 * 256 + ocw + l15) * 256 + c1 + quad * 8));
                aN1 = *(const bf16x8*)(wb + ((size_t)(t1 * 256 + ocw + 16 + l15) * 256 + c1 + quad * 8));
            }

#pragma unroll
            for (int p = 0; p < 4; ++p) {
                bf16x8 b = *(const bf16x8*)(&S[cur][(p * 16 + l15) * 40 + quad * 8]);
                acc[p][0] = __builtin_amdgcn_mfma_f32_16x16x32_bf16(aC0, b, acc[p][0], 0, 0, 0);
                acc[p][1] = __builtin_amdgcn_mfma_f32_16x16x32_bf16(aC1, b, acc[p][1], 0, 0, 0);
            }

            if (have1) {
                float v[8];
#pragma unroll
                for (int i = 0; i < 8; ++i)
                    v[i] = wN0 * bs2f(gN0[i]) + wN1 * bs2f(gN1[i])
                         + wN2 * bs2f(gN2[i]) + wN3 * bs2f(gN3[i]);
                u32x4 r;
#pragma unroll
                for (int i = 0; i < 4; ++i)
                    asm("v_cvt_pk_bf16_f32 %0, %1, %2" : "=v"(r[i]) : "v"(v[2 * i]), "v"(v[2 * i + 1]));
                *(u32x4*)(&S[cur ^ 1][sw]) = r;
            }
            gN0 = gF0; gN1 = gF1; gN2 = gF2; gN3 = gF3;
            wN0 = wF0; wN1 = wF1; wN2 = wF2; wN3 = wF3;
            aC0 = aN0; aC1 = aN1;
            cur ^= 1;
            __syncthreads();
        }
    }

#pragma unroll
    for (int p = 0; p < 4; ++p) {
        const int px = y * HW + xh + p * 16 + l15;
#pragma unroll
        for (int g = 0; g < 2; ++g) {
            const int ocq = ocw + g * 16 + quad * 4;
            short4v s4;
#pragma unroll
            for (int r = 0; r < 4; ++r)
                s4[r] = f2bs(fmaxf(acc[p][g][r] + bb[ocq + r], 0.f));
            *(short4v*)(outa + (size_t)px * 256 + ocq) = s4;
        }
    }
}

// pool: T [px][256] bf16 -> P [px][32] bf16 (max over 8 consecutive oc)
__global__ __launch_bounds__(256) void v10_pool(
    const short* __restrict__ t1, short* __restrict__ p)
{
    int g = blockIdx.x * 256 + threadIdx.x;
    if (g >= 32 * NPX) return;
    int px = g >> 5, c = g & 31;
    const short* q = t1 + (size_t)px * 256 + c * 8;
    float m = bs2f(q[0]);
#pragma unroll
    for (int r = 1; r < 8; ++r) m = fmaxf(m, bs2f(q[r]));
    p[(size_t)px * 32 + c] = f2bs(m);
}

// anchors + refine decode -> fp32 d_out (shared by both paths)
__global__ __launch_bounds__(256) void v9_decode(
    const float* __restrict__ bbox, float* __restrict__ anchors_out,
    float* __restrict__ refine_out, const int* __restrict__ stride_p)
{
    int px = blockIdx.x * 256 + threadIdx.x;
    if (px >= NPX) return;
    float s = (float)(*stride_p);
    int y = px >> 7, x = px & 127;
    anchors_out[px * 5 + 0] = x * s + 3.5f;
    anchors_out[px * 5 + 1] = y * s + 3.5f;
    anchors_out[px * 5 + 2] = 32.f;
    anchors_out[px * 5 + 3] = 32.f;
    anchors_out[px * 5 + 4] = 0.f;
    float gx, gy, gw, gh, ga;
    v9_decode_px(bbox, px, s, gx, gy, gw, gh, ga);
    refine_out[px * 5 + 0] = gx;
    refine_out[px * 5 + 1] = gy;
    refine_out[px * 5 + 2] = gw;
    refine_out[px * 5 + 3] = gh;
    refine_out[px * 5 + 4] = ga;
}

// ===========================================================================
// ============  V9 FALLBACK (verbatim from passing round 9)  ================
// ===========================================================================
template <typename TIN, int RELU, int ORCONV>
__global__ __launch_bounds__(256) void v9_conv3x3(
    const TIN* __restrict__ in, const float* __restrict__ w,
    const float* __restrict__ bias, F8* __restrict__ out, int Cin)
{
    const int y   = blockIdx.x;
    const int ocb = blockIdx.y * 64;
    const int tid = threadIdx.x;
    const int xg  = tid & 15;
    const int og  = tid >> 4;
    const int x0  = xg * 8;
    const int oc0 = ocb + og * 4;

    __shared__ float srow[3][132];
    float acc[4][8];
#pragma unroll
    for (int i = 0; i < 4; ++i)
#pragma unroll
        for (int j = 0; j < 8; ++j) acc[i][j] = 0.f;

    for (int ci = 0; ci < Cin; ++ci) {
        __syncthreads();
        const TIN* inp = in + (size_t)ci * NPX;
        for (int t = tid; t < 3 * 130; t += 256) {
            int r = t / 130, c = t - r * 130;
            int yy = y - 1 + r, xx = c - 1;
            float v = 0.f;
            if (yy >= 0 && yy < HW && xx >= 0 && xx < HW) v = ldg_(inp + yy * HW + xx);
            srow[r][c] = v;
        }
        __syncthreads();
        float wv[4][9];
#pragma unroll
        for (int i = 0; i < 4; ++i) {
            if (ORCONV) {
                int oc = oc0 + i;
                const float* wp = w + ((size_t)(oc >> 3) * Cin + ci) * 9;
                const int* rot = c_ROT9[oc & 7];
#pragma unroll
                for (int k = 0; k < 9; ++k) wv[i][k] = wp[rot[k]];
            } else {
                const float* wp = w + ((size_t)(oc0 + i) * Cin + ci) * 9;
#pragma unroll
                for (int k = 0; k < 9; ++k) wv[i][k] = wp[k];
            }
        }
#pragma unroll
        for (int r = 0; r < 3; ++r) {
            float iv[10];
#pragma unroll
            for (int c = 0; c < 10; ++c) iv[c] = srow[r][x0 + c];
#pragma unroll
            for (int dxk = 0; dxk < 3; ++dxk)
#pragma unroll
                for (int i = 0; i < 4; ++i)
#pragma unroll
                    for (int j = 0; j < 8; ++j)
                        acc[i][j] += iv[j + dxk] * wv[i][r * 3 + dxk];
        }
    }
#pragma unroll
    for (int i = 0; i < 4; ++i) {
        float b = ORCONV ? bias[(oc0 + i) >> 3] : bias[oc0 + i];
#pragma unroll
        for (int j = 0; j < 8; ++j) {
            float v = acc[i][j] + b;
            if (RELU) v = fmaxf(v, 0.f);
            out[(size_t)(oc0 + i) * NPX + y * HW + x0 + j].b = enc8(v);
        }
    }
}

__global__ __launch_bounds__(256) void v9_head1x1(
    const F8* __restrict__ in, const float* __restrict__ w,
    const float* __restrict__ bias, float* __restrict__ out, int Cout)
{
    int g = blockIdx.x * 256 + threadIdx.x;
    if (g >= Cout * NPX) return;
    int px = g & (NPX - 1);
    int oc = g >> 14;
    float acc = bias[oc];
    const float* wp = w + (size_t)oc * CC;
    for (int ci = 0; ci < CC; ++ci)
        acc += dec8(in[(size_t)ci * NPX + px]) * wp[ci];
    out[g] = acc;
}

__global__ __launch_bounds__(256) void v9_head3x3(
    const F8* __restrict__ in, const float* __restrict__ w,
    const float* __restrict__ bias, float* __restrict__ out, int Cout)
{
    int g = blockIdx.x * 256 + threadIdx.x;
    if (g >= Cout * NPX) return;
    int px = g & (NPX - 1);
    int oc = g >> 14;
    int y = px >> 7, x = px & 127;
    float acc = bias[oc];
    for (int ci = 0; ci < CC; ++ci) {
        const F8* ip = in + (size_t)ci * NPX;
        const float* wp = w + ((size_t)oc * CC + ci) * 9;
#pragma unroll
        for (int dy = 0; dy < 3; ++dy) {
            int yy = y + dy - 1;
            if (yy < 0 || yy >= HW) continue;
#pragma unroll
            for (int dxk = 0; dxk < 3; ++dxk) {
                int xx = x + dxk - 1;
                if (xx < 0 || xx >= HW) continue;
                acc += dec8(ip[yy * HW + xx]) * wp[dy * 3 + dxk];
            }
        }
    }
    out[g] = acc;
}

__global__ __launch_bounds__(256) void v9_align(
    const float* __restrict__ in, const float* __restrict__ bbox,
    const float* __restrict__ w, const float* __restrict__ bias,
    const int* __restrict__ stride_p, F8* __restrict__ out)
{
    const int y   = blockIdx.x;
    const int ocb = blockIdx.y * 64;
    const int tid = threadIdx.x;
    const int xg  = tid & 15;
    const int og  = tid >> 4;
    const int x0  = xg * 8;
    const int oc0 = ocb + og * 4;

    __shared__ float smp[9][128];
    __shared__ int   s_ix[1152], s_iy[1152];
    __shared__ float s_wx1[1152], s_wy1[1152];

    const float s = (float)(*stride_p);
    for (int t = tid; t < 1152; t += 256) {
        int k = t >> 7, xx = t & 127;
        int px = y * HW + xx;
        float gx, gy, gw, gh, ga;
        v9_decode_px(bbox, px, s, gx, gy, gw, gh, ga);
        float axc = gx / s, ayc = gy / s;
        float aw3 = gw / (s * 3.f), ah3 = gh / (s * 3.f);
        float cs = cosf(ga), sn = sinf(ga);
        float kx = (float)(k % 3 - 1), ky = (float)(k / 3 - 1);
        float ddx = aw3 * kx, ddy = ah3 * ky;
        float xf = cs * ddx - sn * ddy + axc;
        float yf = sn * ddx + cs * ddy + ayc;
        float fx = floorf(xf), fy = floorf(yf);
        s_ix[t]  = (int)fx;
        s_iy[t]  = (int)fy;
        s_wx1[t] = xf - fx;
        s_wy1[t] = yf - fy;
    }

    float acc[4][8];
#pragma unroll
    for (int i = 0; i < 4; ++i)
#pragma unroll
        for (int j = 0; j < 8; ++j) acc[i][j] = 0.f;

    for (int ci = 0; ci < CC; ++ci) {
        __syncthreads();
        const float* ip = in + (size_t)ci * NPX;
        for (int t = tid; t < 1152; t += 256) {
            int ix = s_ix[t], iy = s_iy[t];
            float wx1 = s_wx1[t], wx0 = 1.f - wx1;
            float wy1 = s_wy1[t], wy0 = 1.f - wy1;
            float v = 0.f;
            bool xv0 = (ix >= 0) && (ix < HW);
            bool xv1 = (ix + 1 >= 0) && (ix + 1 < HW);
            bool yv0 = (iy >= 0) && (iy < HW);
            bool yv1 = (iy + 1 >= 0) && (iy + 1 < HW);
            if (yv0 && xv0) v += ip[iy * HW + ix] * wy0 * wx0;
            if (yv0 && xv1) v += ip[iy * HW + ix + 1] * wy0 * wx1;
            if (yv1 && xv0) v += ip[(iy + 1) * HW + ix] * wy1 * wx0;
            if (yv1 && xv1) v += ip[(iy + 1) * HW + ix + 1] * wy1 * wx1;
            smp[t >> 7][t & 127] = v;
        }
        __syncthreads();

        float wv[4][9];
#pragma unroll
        for (int i = 0; i < 4; ++i) {
            const float* wp = w + ((size_t)(oc0 + i) * CC + ci) * 9;
#pragma unroll
            for (int k = 0; k < 9; ++k) wv[i][k] = wp[k];
        }
#pragma unroll
        for (int k = 0; k < 9; ++k) {
            float iv[8];
#pragma unroll
            for (int j = 0; j < 8; ++j) iv[j] = smp[k][x0 + j];
#pragma unroll
            for (int i = 0; i < 4; ++i)
#pragma unroll
                for (int j = 0; j < 8; ++j)
                    acc[i][j] += iv[j] * wv[i][k];
        }
    }
#pragma unroll
    for (int i = 0; i < 4; ++i) {
        float b = bias[oc0 + i];
#pragma unroll
        for (int j = 0; j < 8; ++j)
            out[(size_t)(oc0 + i) * NPX + y * HW + x0 + j].b =
                enc8(fmaxf(acc[i][j] + b, 0.f));
    }
}

__global__ __launch_bounds__(256) void v9_pool(
    const F8* __restrict__ orf, F8* __restrict__ pooled)
{
    int g = blockIdx.x * 256 + threadIdx.x;
    if (g >= 32 * NPX) return;
    int px = g & (NPX - 1);
    int c  = g >> 14;
    float m = -3.4e38f;
#pragma unroll
    for (int r = 0; r < 8; ++r)
        m = fmaxf(m, dec8(orf[(size_t)(c * 8 + r) * NPX + px]));
    pooled[g].b = enc8(m);
}

// ===========================================================================
extern "C" void kernel_launch(void* const* d_in, const int* in_sizes, int n_in,
                              void* d_out, int out_size, void* d_ws, size_t ws_size,
                              hipStream_t stream)
{
    const float* feats = (const float*)d_in[0];
    const float* frw0 = (const float*)d_in[1];  const float* frb0 = (const float*)d_in[2];
    const float* frw1 = (const float*)d_in[3];  const float* frb1 = (const float*)d_in[4];
    const float* frhw = (const float*)d_in[5];  const float* frhb = (const float*)d_in[6];
    const float* fcw0 = (const float*)d_in[7];  const float* fcb0 = (const float*)d_in[8];
    const float* fcw1 = (const float*)d_in[9];  const float* fcb1 = (const float*)d_in[10];
    const float* fchw = (const float*)d_in[11]; const float* fchb = (const float*)d_in[12];
    const float* alw  = (const float*)d_in[13]; const float* alb  = (const float*)d_in[14];
    const float* orw  = (const float*)d_in[15]; const float* orb  = (const float*)d_in[16];
    const float* drw0 = (const float*)d_in[17]; const float* drb0 = (const float*)d_in[18];
    const float* drw1 = (const float*)d_in[19]; const float* drb1 = (const float*)d_in[20];
    const float* drhw = (const float*)d_in[21]; const float* drhb = (const float*)d_in[22];
    const float* dcw0 = (const float*)d_in[23]; const float* dcb0 = (const float*)d_in[24];
    const float* dcw1 = (const float*)d_in[25]; const float* dcb1 = (const float*)d_in[26];
    const float* dchw = (const float*)d_in[27]; const float* dchb = (const float*)d_in[28];
    const int*  stride_p = (const int*)d_in[29];

    float* out = (float*)d_out;   // fp32 output (proven round 8/9)
    float* o_fam_cls  = out;
    float* o_fam_bbox = out + 245760;
    float* o_odm_cls  = out + 327680;
    float* o_odm_bbox = out + 573440;
    float* o_anchors  = out + 655360;
    float* o_refine   = out + 737280;

    dim3 blk(256), blk8(512);

    const size_t NEED3     = 55097344;   // paired-branch layout (5 act buffers)
    const size_t NEED2     = 38172672;   // fused-prep weight arena layout
    const size_t NEED_FAST = 27395072;
    const size_t NEED_V9   = 8912896;

    if (ws_size >= NEED3) {
        char* ws = (char*)d_ws;
        short* xt = (short*)(ws + 0);
        short* T0 = (short*)(ws + 8388608);
        short* T1 = (short*)(ws + 16777216);
        short* T2 = (short*)(ws + 25165824);
        short* T3 = (short*)(ws + 33554432);
        short* P  = (short*)(ws + 41943040);   // [16384][32]
        short* WA = (short*)(ws + 42991616);   // fused weight arena (11.94 MB)
        float* BA = (float*)(ws + 55083008);   // 14 x 256 fp32 biases

        v12_prepall<<<dim3(2304, 14), blk, 0, stream>>>(
            frw0, frw1, fcw0, fcw1, alw, orw, drw0, drw1, dcw1,
            frhw, fchw, drhw, dchw, dcw0,
            frb0, frb1, fcb0, fcb1, alb, orb, drb0, drb1, dcb1,
            frhb, fchb, drhb, dchb, dcb0,
            WA, BA);
        v10_transpose<<<dim3(512, 8), blk, 0, stream>>>(feats, xt);

        // FAM conv0 (reg + cls), conv1 (reg + cls) — 8-wave, 16 waves/CU
        v15_pair<1, 256, 256><<<dim3(256, 2), blk8, 0, stream>>>(
            xt, xt, WA + 0, WA + 1179648, BA + 0 * 256, BA + 2 * 256, T0, T2);
        v15_pair<1, 256, 256><<<dim3(256, 2), blk8, 0, stream>>>(
            T0, T2, WA + 589824, WA + 1769472, BA + 1 * 256, BA + 3 * 256, T1, T3);
        v13_pair<0, 1, 1, 256, 256, 1, 1, 64><<<dim3(256, 2), blk, 0, stream>>>(
            T1, T3, WA + 5308416, WA + 5455872, BA + 9 * 256, BA + 10 * 256,
            o_fam_bbox, o_fam_cls, 5, 15);
        // decode
        v9_decode<<<dim3(64), blk, 0, stream>>>(o_fam_bbox, o_anchors, o_refine, stride_p);
        // align conv -> T0
        v13_align<<<dim3(256, 2), blk, 0, stream>>>(xt, o_fam_bbox, WA + 2359296, BA + 4 * 256, stride_p, T0);
        // OR conv -> T1, no relu — 8-wave
        v15_conv<0, 256><<<dim3(256, 1), blk8, 0, stream>>>(T0, WA + 2949120, BA + 5 * 256, T1);
        // pool -> P
        v10_pool<<<dim3(2048), blk, 0, stream>>>(T1, P);
        // ODM conv0 (reg Cin=256 + cls Cin=32), conv1 (reg + cls), heads
        v15_pair<1, 256, 32><<<dim3(256, 2), blk8, 0, stream>>>(
            T1, P, WA + 3538944, WA + 5898240, BA + 6 * 256, BA + 13 * 256, T0, T2);
        v15_pair<1, 256, 256><<<dim3(256, 2), blk8, 0, stream>>>(
            T0, T2, WA + 4128768, WA + 4718592, BA + 7 * 256, BA + 8 * 256, T1, T3);
        v13_pair<0, 1, 0, 256, 256, 1, 1, 64><<<dim3(256, 2), blk, 0, stream>>>(
            T1, T3, WA + 5603328, WA + 5750784, BA + 11 * 256, BA + 12 * 256,
            o_odm_bbox, o_odm_cls, 5, 15);
    } else if (ws_size >= NEED2) {
        char* ws = (char*)d_ws;
        short* xt = (short*)(ws + 0);
        short* T0 = (short*)(ws + 8388608);
        short* T1 = (short*)(ws + 16777216);
        short* P  = (short*)(ws + 25165824);
        short* WA = (short*)(ws + 26214400);
        float* BA = (float*)(ws + 38158336);

        dim3 gc(256, 2), gh(256, 1);

        v12_prepall<<<dim3(2304, 14), blk, 0, stream>>>(
            frw0, frw1, fcw0, fcw1, alw, orw, drw0, drw1, dcw1,
            frhw, fchw, drhw, dchw, dcw0,
            frb0, frb1, fcb0, fcb1, alb, orb, drb0, drb1, dcb1,
            frhb, fchb, drhb, dchb, dcb0,
            WA, BA);
        v10_transpose<<<dim3(512, 8), blk, 0, stream>>>(feats, xt);

        v13_conv<1, 0, 0, 256, 2><<<gc, blk, 0, stream>>>(xt, WA + 0,       BA + 0 * 256, T0, 256, 256);
        v13_conv<1, 0, 0, 256, 2><<<gc, blk, 0, stream>>>(T0, WA + 589824,  BA + 1 * 256, T1, 256, 256);
        v13_conv<0, 1, 1, 256, 1><<<gh, blk, 0, stream>>>(T1, WA + 5308416, BA + 9 * 256, o_fam_bbox, 5, 64);
        v13_conv<1, 0, 0, 256, 2><<<gc, blk, 0, stream>>>(xt, WA + 1179648, BA + 2 * 256, T0, 256, 256);
        v13_conv<1, 0, 0, 256, 2><<<gc, blk, 0, stream>>>(T0, WA + 1769472, BA + 3 * 256, T1, 256, 256);
        v13_conv<0, 1, 1, 256, 1><<<gh, blk, 0, stream>>>(T1, WA + 5455872, BA + 10 * 256, o_fam_cls, 15, 64);
        v9_decode<<<dim3(64), blk, 0, stream>>>(o_fam_bbox, o_anchors, o_refine, stride_p);
        v13_align<<<dim3(256, 2), blk, 0, stream>>>(xt, o_fam_bbox, WA + 2359296, BA + 4 * 256, stride_p, T0);
        v13_conv<0, 0, 0, 256, 2><<<gc, blk, 0, stream>>>(T0, WA + 2949120, BA + 5 * 256, T1, 256, 256);
        v10_pool<<<dim3(2048), blk, 0, stream>>>(T1, P);
        v13_conv<1, 0, 0, 256, 2><<<gc, blk, 0, stream>>>(T1, WA + 3538944, BA + 6 * 256, T0, 256, 256);
        v13_conv<1, 0, 0, 256, 2><<<gc, blk, 0, stream>>>(T0, WA + 4128768, BA + 7 * 256, T1, 256, 256);
        v13_conv<0, 1, 0, 256, 1><<<gh, blk, 0, stream>>>(T1, WA + 5603328, BA + 11 * 256, o_odm_bbox, 5, 64);
        v13_conv<1, 0, 0, 32, 2><<<gc, blk, 0, stream>>>(P, WA + 5898240, BA + 13 * 256, T0, 256, 256);
        v13_conv<1, 0, 0, 256, 2><<<gc, blk, 0, stream>>>(T0, WA + 4718592, BA + 8 * 256, T1, 256, 256);
        v13_conv<0, 1, 0, 256, 1><<<gh, blk, 0, stream>>>(T1, WA + 5750784, BA + 12 * 256, o_odm_cls, 15, 64);
    } else if (ws_size >= NEED_FAST) {
        char* ws = (char*)d_ws;
        short* xt = (short*)(ws + 0);
        short* T0 = (short*)(ws + 8388608);
        short* T1 = (short*)(ws + 16777216);
        short* P  = (short*)(ws + 25165824);
        short* WB = (short*)(ws + 26214400);
        float* BB = (float*)(ws + 27394048);

        dim3 gc(256, 2), gh(256, 1);

        v10_transpose<<<dim3(512, 8), blk, 0, stream>>>(feats, xt);

#define PREP(W, B, COUT, CIN, OCP, MODE) \
        v10_prep<<<dim3((9 * (OCP) * (CIN) + 255) / 256), blk, 0, stream>>>( \
            W, B, WB, BB, COUT, CIN, OCP, MODE)

        PREP(frw0, frb0, 256, 256, 256, 0);
        v13_conv<1, 0, 0, 256, 2><<<gc, blk, 0, stream>>>(xt, WB, BB, T0, 256, 256);
        PREP(frw1, frb1, 256, 256, 256, 0);
        v13_conv<1, 0, 0, 256, 2><<<gc, blk, 0, stream>>>(T0, WB, BB, T1, 256, 256);
        PREP(frhw, frhb, 5, 256, 64, 2);
        v13_conv<0, 1, 1, 256, 1><<<gh, blk, 0, stream>>>(T1, WB, BB, o_fam_bbox, 5, 64);
        PREP(fcw0, fcb0, 256, 256, 256, 0);
        v13_conv<1, 0, 0, 256, 2><<<gc, blk, 0, stream>>>(xt, WB, BB, T0, 256, 256);
        PREP(fcw1, fcb1, 256, 256, 256, 0);
        v13_conv<1, 0, 0, 256, 2><<<gc, blk, 0, stream>>>(T0, WB, BB, T1, 256, 256);
        PREP(fchw, fchb, 15, 256, 64, 2);
        v13_conv<0, 1, 1, 256, 1><<<gh, blk, 0, stream>>>(T1, WB, BB, o_fam_cls, 15, 64);
        v9_decode<<<dim3(64), blk, 0, stream>>>(o_fam_bbox, o_anchors, o_refine, stride_p);
        PREP(alw, alb, 256, 256, 256, 0);
        v13_align<<<dim3(256, 2), blk, 0, stream>>>(xt, o_fam_bbox, WB, BB, stride_p, T0);
        PREP(orw, orb, 256, 256, 256, 1);
        v13_conv<0, 0, 0, 256, 2><<<gc, blk, 0, stream>>>(T0, WB, BB, T1, 256, 256);
        v10_pool<<<dim3(2048), blk, 0, stream>>>(T1, P);
        PREP(drw0, drb0, 256, 256, 256, 0);
        v13_conv<1, 0, 0, 256, 2><<<gc, blk, 0, stream>>>(T1, WB, BB, T0, 256, 256);
        PREP(drw1, drb1, 256, 256, 256, 0);
        v13_conv<1, 0, 0, 256, 2><<<gc, blk, 0, stream>>>(T0, WB, BB, T1, 256, 256);
        PREP(drhw, drhb, 5, 256, 64, 0);
        v13_conv<0, 1, 0, 256, 1><<<gh, blk, 0, stream>>>(T1, WB, BB, o_odm_bbox, 5, 64);
        PREP(dcw0, dcb0, 256, 32, 256, 0);
        v13_conv<1, 0, 0, 32, 2><<<gc, blk, 0, stream>>>(P, WB, BB, T0, 256, 256);
        PREP(dcw1, dcb1, 256, 256, 256, 0);
        v13_conv<1, 0, 0, 256, 2><<<gc, blk, 0, stream>>>(T0, WB, BB, T1, 256, 256);
        PREP(dchw, dchb, 15, 256, 64, 0);
        v13_conv<0, 1, 0, 256, 1><<<gh, blk, 0, stream>>>(T1, WB, BB, o_odm_cls, 15, 64);
#undef PREP
    } else if (ws_size >= NEED_V9) {
        // -------- verbatim round-9 passing path --------
        F8* A = (F8*)d_ws;
        F8* B = (F8*)((char*)d_ws + 4194304);
        F8* P = (F8*)((char*)d_ws + 8388608);
        dim3 gconv(128, 4);

        v9_conv3x3<float, 1, 0><<<gconv, blk, 0, stream>>>(feats, frw0, frb0, A, 256);
        v9_conv3x3<F8,    1, 0><<<gconv, blk, 0, stream>>>(A, frw1, frb1, B, 256);
        v9_head1x1<<<dim3(5 * 64), blk, 0, stream>>>(B, frhw, frhb, o_fam_bbox, 5);
        v9_conv3x3<float, 1, 0><<<gconv, blk, 0, stream>>>(feats, fcw0, fcb0, A, 256);
        v9_conv3x3<F8,    1, 0><<<gconv, blk, 0, stream>>>(A, fcw1, fcb1, B, 256);
        v9_head1x1<<<dim3(15 * 64), blk, 0, stream>>>(B, fchw, fchb, o_fam_cls, 15);
        v9_decode<<<dim3(64), blk, 0, stream>>>(o_fam_bbox, o_anchors, o_refine, stride_p);
        v9_align<<<gconv, blk, 0, stream>>>(feats, o_fam_bbox, alw, alb, stride_p, A);
        v9_conv3x3<F8, 0, 1><<<gconv, blk, 0, stream>>>(A, orw, orb, B, 256);
        v9_pool<<<dim3(2048), blk, 0, stream>>>(B, P);
        v9_conv3x3<F8, 1, 0><<<gconv, blk, 0, stream>>>(B, drw0, drb0, A, 256);
        v9_conv3x3<F8, 1, 0><<<gconv, blk, 0, stream>>>(A, drw1, drb1, B, 256);
        v9_head3x3<<<dim3(5 * 64), blk, 0, stream>>>(B, drhw, drhb, o_odm_bbox, 5);
        v9_conv3x3<F8, 1, 0><<<gconv, blk, 0, stream>>>(P, dcw0, dcb0, A, 32);
        v9_conv3x3<F8, 1, 0><<<gconv, blk, 0, stream>>>(A, dcw1, dcb1, B, 256);
        v9_head3x3<<<dim3(15 * 64), blk, 0, stream>>>(B, dchw, dchb, o_odm_cls, 15);
    }
}